// Round 14
// baseline (608.326 us; speedup 1.0000x reference)
//
#include <hip/hip_runtime.h>

#define TT 215
#define BB 256
#define ROWS (TT * BB)  // 55040 = 860 * 64

typedef __attribute__((ext_vector_type(8))) short short8;   // 8 bf16 = 4 VGPRs
typedef __attribute__((ext_vector_type(4))) float f32x4;    // MFMA acc

__device__ __forceinline__ unsigned short f2bf_rn(float x) {
    unsigned int u = __float_as_uint(x);
    u = u + 0x7FFFu + ((u >> 16) & 1u);   // round-to-nearest-even bf16
    return (unsigned short)(u >> 16);
}
__device__ __forceinline__ float bf2f(unsigned short b) {
    return __uint_as_float(((unsigned int)b) << 16);
}
__device__ __forceinline__ float bflo(unsigned int u) {  // low short -> f32
    return __uint_as_float(u << 16);
}
__device__ __forceinline__ float bfhi(unsigned int u) {  // high short -> f32
    return __uint_as_float(u & 0xffff0000u);
}

// ---------------------------------------------------------------- one-shot prep: timescales + split-bf16 weights
// enc_in [2][216][96], ff1 [2][128][96], ff2 [2][72][128], Wout [2][72][96]
__global__ void k_prep(const float* __restrict__ enc_in_w, const float* __restrict__ ff1_w,
                       const float* __restrict__ ff2_w, const float* __restrict__ enc_out_w,
                       unsigned short* __restrict__ Whi, unsigned short* __restrict__ Wlo,
                       unsigned short* __restrict__ F1hi, unsigned short* __restrict__ F1lo,
                       unsigned short* __restrict__ F2hi, unsigned short* __restrict__ F2lo,
                       unsigned short* __restrict__ Ohi, unsigned short* __restrict__ Olo,
                       float* __restrict__ ts) {
    int g = blockIdx.x * 256 + threadIdx.x;
    if (g < 18) ts[g] = (float)pow(215.0, (double)g / 17.0);  // matches np float64 215**linspace
    if (g < 2 * 216 * 96) {
        int l = g / (216 * 96), rem = g % (216 * 96);
        int o = rem / 96, k = rem % 96;
        float v = (k < 72) ? enc_in_w[((size_t)l * 216 + o) * 72 + k] : 0.f;
        unsigned short hi = f2bf_rn(v);
        Whi[g] = hi; Wlo[g] = f2bf_rn(v - bf2f(hi));
    }
    if (g < 2 * 128 * 96) {
        int l = g / (128 * 96), rem = g % (128 * 96);
        int j = rem / 96, k = rem % 96;
        float v = (k < 72) ? ff1_w[((size_t)l * 128 + j) * 72 + k] : 0.f;
        unsigned short hi = f2bf_rn(v);
        F1hi[g] = hi; F1lo[g] = f2bf_rn(v - bf2f(hi));
    }
    if (g < 2 * 72 * 128) {  // ff2 already [o][j] = B[n][k], K=128
        float v = ff2_w[g];
        unsigned short hi = f2bf_rn(v);
        F2hi[g] = hi; F2lo[g] = f2bf_rn(v - bf2f(hi));
    }
    if (g < 2 * 72 * 96) {
        int l = g / (72 * 96), rem = g % (72 * 96);
        int o = rem / 96, k = rem % 96;
        float v = (k < 72) ? enc_out_w[((size_t)l * 72 + o) * 72 + k] : 0.f;
        unsigned short hi = f2bf_rn(v);
        Ohi[g] = hi; Olo[g] = f2bf_rn(v - bf2f(hi));
    }
}

// ---------------------------------------------------------------- x = (src[:,:,:36] @ W_enc.T + b)*6 ; grid (215,4)
__global__ __launch_bounds__(256, 1) void k_enc1(const float* __restrict__ src,
                                                 const float* __restrict__ W,
                                                 const float* __restrict__ bias,
                                                 float* __restrict__ x) {
    int row = blockIdx.x * 256 + threadIdx.x;
    int o0 = blockIdx.y * 9;
    float s[36];
    const float4* sv = (const float4*)(src + (size_t)row * 72);
#pragma unroll
    for (int k = 0; k < 9; ++k) {
        float4 v = sv[k];
        s[4 * k] = v.x; s[4 * k + 1] = v.y; s[4 * k + 2] = v.z; s[4 * k + 3] = v.w;
    }
    float* xp = x + (size_t)row * 36 + o0;
#pragma unroll
    for (int o = 0; o < 9; ++o) {
        float a = bias[o0 + o];
        const float* w = W + (size_t)(o0 + o) * 36;
#pragma unroll
        for (int i = 0; i < 36; ++i) a = fmaf(s[i], w[i], a);
        xp[o] = a * 6.0f;
    }
}

// ---------------------------------------------------------------- h[:,:, :36] = x @ Wskip.T + b ; grid (215,4)
__global__ __launch_bounds__(256, 1) void k_enc2(const float* __restrict__ x,
                                                 const float* __restrict__ W,
                                                 const float* __restrict__ bias,
                                                 float* __restrict__ h) {
    int row = blockIdx.x * 256 + threadIdx.x;
    int o0 = blockIdx.y * 9;
    float xr[36];
    const float4* xv = (const float4*)(x + (size_t)row * 36);
#pragma unroll
    for (int k = 0; k < 9; ++k) {
        float4 v = xv[k];
        xr[4 * k] = v.x; xr[4 * k + 1] = v.y; xr[4 * k + 2] = v.z; xr[4 * k + 3] = v.w;
    }
    float* hp = h + (size_t)row * 72 + o0;
#pragma unroll
    for (int o = 0; o < 9; ++o) {
        float a = bias[o0 + o];
        const float* w = W + (size_t)(o0 + o) * 36;
#pragma unroll
        for (int i = 0; i < 36; ++i) a = fmaf(xr[i], w[i], a);
        hp[o] = a;
    }
}

// ---------------------------------------------------------------- h[:,:,36:] = pe ; elementwise
__global__ __launch_bounds__(256) void k_pe(const float* __restrict__ times,
                                            const float* __restrict__ ts,
                                            float* __restrict__ h) {
    int idx = blockIdx.x * 256 + threadIdx.x;  // < ROWS*36
    int d = idx % 36, row = idx / 36;
    float t = times[row];
    float val;
    if (d < 18) val = sinf(t / ts[d]);
    else        val = cosf(t / ts[d - 18]);
    h[(size_t)row * 72 + 36 + d] = val;
}

// ---------------------------------------------------------------- graph q|k|v ; grid (36, 12): mat = y>>2, o0 = (y&3)*9
__global__ __launch_bounds__(256, 1) void k_graph_qkv(const float* __restrict__ x,
                                                      const float* __restrict__ Wq, const float* __restrict__ bq,
                                                      const float* __restrict__ Wk, const float* __restrict__ bk,
                                                      const float* __restrict__ Wv, const float* __restrict__ bv,
                                                      float* __restrict__ qg, float* __restrict__ kg,
                                                      float* __restrict__ vg) {
    int row = blockIdx.x * 256 + threadIdx.x;  // < 9216
    int mat = blockIdx.y >> 2;
    int o0 = (blockIdx.y & 3) * 9;
    const float* W; const float* bias; float* out;
    if (mat == 0)      { W = Wq; bias = bq; out = qg; }
    else if (mat == 1) { W = Wk; bias = bk; out = kg; }
    else               { W = Wv; bias = bv; out = vg; }
    float xr[36];
    const float4* xv = (const float4*)(x + (size_t)row * 36);
#pragma unroll
    for (int k = 0; k < 9; ++k) {
        float4 v = xv[k];
        xr[4 * k] = v.x; xr[4 * k + 1] = v.y; xr[4 * k + 2] = v.z; xr[4 * k + 3] = v.w;
    }
    float* op = out + (size_t)row * 36 + o0;
#pragma unroll
    for (int o = 0; o < 9; ++o) {
        float a = bias[o0 + o];
        const float* w = W + (size_t)(o0 + o) * 36;
#pragma unroll
        for (int i = 0; i < 36; ++i) a = fmaf(xr[i], w[i], a);
        op[o] = a;
    }
}

// ---------------------------------------------------------------- graph attention per batch; h[:36,:,:36] += msg
__global__ void k_graph_attn(const float* __restrict__ qg, const float* __restrict__ kg,
                             const float* __restrict__ vg, float* __restrict__ h,
                             float* __restrict__ Abuf, float* __restrict__ sqv) {
    __shared__ float q[1296], k[1296], v[1296], A[1296];
    __shared__ float red[128];
    int b = blockIdx.x, tid = threadIdx.x;
    for (int i = tid; i < 1296; i += 128) {
        int t = i / 36, e = i % 36;
        int g = (t * BB + b) * 36 + e;
        q[i] = qg[g]; k[i] = kg[g]; v[i] = vg[g];
    }
    __syncthreads();
    for (int i = tid; i < 1296; i += 128) {
        int r = i / 36, c = i % 36;
        float a = 0.f;
#pragma unroll
        for (int e = 0; e < 36; ++e) a = fmaf(q[r * 36 + e], k[c * 36 + e], a);
        A[i] = a * (1.0f / 6.0f);
    }
    __syncthreads();
    if (tid < 36) {
        float m = -1e30f;
        for (int j = 0; j < 36; ++j) m = fmaxf(m, A[tid * 36 + j]);
        float s = 0.f;
        for (int j = 0; j < 36; ++j) { float e = expf(A[tid * 36 + j] - m); A[tid * 36 + j] = e; s += e; }
        float inv = 1.0f / s;
        for (int j = 0; j < 36; ++j) A[tid * 36 + j] *= inv;
    }
    __syncthreads();
    float lsq = 0.f;
    for (int i = tid; i < 1296; i += 128) {
        float a = A[i];
        Abuf[(size_t)b * 1296 + i] = a;
        lsq = fmaf(a, a, lsq);
        int r = i / 36, e = i % 36;
        float m = 0.f;
#pragma unroll
        for (int j = 0; j < 36; ++j) m = fmaf(A[r * 36 + j], v[j * 36 + e], m);
        h[((size_t)r * BB + b) * 72 + e] += m;
    }
    red[tid] = lsq;
    __syncthreads();
    for (int s = 64; s > 0; s >>= 1) { if (tid < s) red[tid] += red[tid + s]; __syncthreads(); }
    if (tid == 0) sqv[b] = red[0];
}

// ---------------------------------------------------------------- Gram row + per-row distance partial sum
__global__ void k_gram(const float* __restrict__ Abuf, const float* __restrict__ sqv,
                       float* __restrict__ rowsum) {
    __shared__ float Arow[1296];
    __shared__ float red[256];
    int b1 = blockIdx.x, tid = threadIdx.x;
    for (int i = tid; i < 1296; i += 256) Arow[i] = Abuf[(size_t)b1 * 1296 + i];
    __syncthreads();
    int b2 = tid;
    const float* a2 = Abuf + (size_t)b2 * 1296;
    float dot = 0.f;
    for (int e = 0; e < 1296; ++e) dot = fmaf(Arow[e], a2[e], dot);
    float d2 = fmaxf(sqv[b1] + sqv[b2] - 2.0f * dot, 0.0f);
    red[tid] = (d2 > 0.0f) ? sqrtf(d2) : 0.0f;
    __syncthreads();
    for (int s = 128; s > 0; s >>= 1) { if (tid < s) red[tid] += red[tid + s]; __syncthreads(); }
    if (tid == 0) rowsum[b1] = red[0];
}

// ---------------------------------------------------------------- qkv = h @ W_in.T + b ; MFMA split-bf16
__global__ __launch_bounds__(256, 1) void k_qkv(const float* __restrict__ h,
                                                const unsigned short* __restrict__ Whi,
                                                const unsigned short* __restrict__ Wlo,
                                                const float* __restrict__ bias,
                                                float* __restrict__ qkv) {
    int tid = threadIdx.x;
    int w = tid >> 6;
    int lane = tid & 63;
    int n16 = lane & 15;
    int quad = lane >> 4;
    int m0 = blockIdx.x * 64 + w * 16;
    int r = m0 + n16;
    short8 Ahi[3], Alo[3];
#pragma unroll
    for (int s = 0; s < 3; ++s) {
        int k0 = s * 32 + quad * 8;
        float v[8];
        if (k0 < 72) {
            const float4* ap = (const float4*)(h + (size_t)r * 72 + k0);
            float4 v0 = ap[0], v1 = ap[1];
            v[0] = v0.x; v[1] = v0.y; v[2] = v0.z; v[3] = v0.w;
            v[4] = v1.x; v[5] = v1.y; v[6] = v1.z; v[7] = v1.w;
        } else {
#pragma unroll
            for (int j = 0; j < 8; ++j) v[j] = 0.f;
        }
        short8 ph, pl;
#pragma unroll
        for (int j = 0; j < 8; ++j) {
            unsigned short hi = f2bf_rn(v[j]);
            ph[j] = (short)hi;
            pl[j] = (short)f2bf_rn(v[j] - bf2f(hi));
        }
        Ahi[s] = ph; Alo[s] = pl;
    }
    f32x4 acc[14];
#pragma unroll
    for (int t = 0; t < 14; ++t) acc[t] = (f32x4){0.f, 0.f, 0.f, 0.f};
#pragma unroll
    for (int t = 0; t < 14; ++t) {
        int o = t * 16 + n16;
        int oc = (o > 215) ? 215 : o;
        const short8* bh = (const short8*)(Whi + (size_t)oc * 96);
        const short8* bl = (const short8*)(Wlo + (size_t)oc * 96);
        f32x4 a = acc[t];
#pragma unroll
        for (int s = 0; s < 3; ++s) {
            short8 Bh = bh[s * 4 + quad];
            short8 Bl = bl[s * 4 + quad];
            a = __builtin_amdgcn_mfma_f32_16x16x32_bf16(Ahi[s], Bh, a, 0, 0, 0);
            a = __builtin_amdgcn_mfma_f32_16x16x32_bf16(Ahi[s], Bl, a, 0, 0, 0);
            a = __builtin_amdgcn_mfma_f32_16x16x32_bf16(Alo[s], Bh, a, 0, 0, 0);
        }
        acc[t] = a;
    }
#pragma unroll
    for (int t = 0; t < 14; ++t) {
        int col = t * 16 + n16;
        if (col < 216) {
            float b = bias[col];
#pragma unroll
            for (int reg = 0; reg < 4; ++reg) {
                int row = m0 + quad * 4 + reg;
                qkv[(size_t)row * 216 + col] = acc[t][reg] + b;
            }
        }
    }
}

// ---------------------------------------------------------------- masked MHA v5: 4 waves/block; wave-pairs split the
// KEY range (partials combine linearly: no online max, scores bounded);
// sub-wave picks query slots. KV bf16 in LDS (5 x b128 per key).
template <int NS>
__device__ __forceinline__ void attn_core(const unsigned short* __restrict__ KV,
                                          const float q[2][18], float acc[2][18],
                                          float l[2], int kbeg, int kend) {
    for (int s = kbeg; s < kend; ++s) {
        const uint4* kvp = (const uint4*)(KV + s * 40);
        uint4 u0 = kvp[0], u1 = kvp[1], u2 = kvp[2], u3 = kvp[3], u4 = kvp[4];
        float kf[18], vf[18];
        kf[0] = bflo(u0.x); kf[1] = bfhi(u0.x); kf[2] = bflo(u0.y); kf[3] = bfhi(u0.y);
        kf[4] = bflo(u0.z); kf[5] = bfhi(u0.z); kf[6] = bflo(u0.w); kf[7] = bfhi(u0.w);
        kf[8] = bflo(u1.x); kf[9] = bfhi(u1.x); kf[10] = bflo(u1.y); kf[11] = bfhi(u1.y);
        kf[12] = bflo(u1.z); kf[13] = bfhi(u1.z); kf[14] = bflo(u1.w); kf[15] = bfhi(u1.w);
        kf[16] = bflo(u2.x); kf[17] = bfhi(u2.x);  // u2.y = pad
        vf[0] = bflo(u2.z); vf[1] = bfhi(u2.z); vf[2] = bflo(u2.w); vf[3] = bfhi(u2.w);
        vf[4] = bflo(u3.x); vf[5] = bfhi(u3.x); vf[6] = bflo(u3.y); vf[7] = bfhi(u3.y);
        vf[8] = bflo(u3.z); vf[9] = bfhi(u3.z); vf[10] = bflo(u3.w); vf[11] = bfhi(u3.w);
        vf[12] = bflo(u4.x); vf[13] = bfhi(u4.x); vf[14] = bflo(u4.y); vf[15] = bfhi(u4.y);
        vf[16] = bflo(u4.z); vf[17] = bfhi(u4.z);  // u4.w = pad
        float p[NS];
#pragma unroll
        for (int j = 0; j < NS; ++j) {
            float sa = 0.f, sb = 0.f;  // 2 partial chains shorten dependency
#pragma unroll
            for (int d = 0; d < 9; ++d) {
                sa = fmaf(q[j][d], kf[d], sa);
                sb = fmaf(q[j][9 + d], kf[9 + d], sb);
            }
            p[j] = __expf(sa + sb);
            l[j] += p[j];
        }
#pragma unroll
        for (int d = 0; d < 18; ++d) {
#pragma unroll
            for (int j = 0; j < NS; ++j) acc[j][d] = fmaf(p[j], vf[d], acc[j][d]);
        }
    }
}

__global__ __launch_bounds__(256, 1) void k_attn(const float* __restrict__ qkv,
                                                 const int* __restrict__ lengths,
                                                 float* __restrict__ ctx) {
    __shared__ unsigned short KV[TT * 40];  // per key: 18 K bf16, 2 pad, 18 V bf16, 2 pad (80B = 5 x uint4)
    __shared__ float pA[2][128][19];        // pair-1 partial acc (stride 19: conflict-free scalar)
    __shared__ float pL[2][128];            // pair-1 partial l
    int b = blockIdx.x & (BB - 1);
    int hh = blockIdx.x >> 8;
    int tid = threadIdx.x;
    int len = lengths[b];
    int n40 = len * 40;
    for (int i = tid; i < n40; i += 256) {
        int s = i / 40, d = i % 40;
        unsigned short v = 0;
        if (d < 18) {
            v = f2bf_rn(qkv[((size_t)s * BB + b) * 216 + hh * 18 + 72 + d]);
        } else if (d >= 20 && d < 38) {
            v = f2bf_rn(qkv[((size_t)s * BB + b) * 216 + hh * 18 + 144 + (d - 20)]);
        }
        KV[i] = v;
    }
    __syncthreads();
    int w = tid >> 6;
    int lane = tid & 63;
    int pair = w >> 1;             // 0: keys [0,half) ; 1: keys [half,len)
    int sub = w & 1;               // query sub-range within slot
    int half = (len + 1) >> 1;
    int kbeg = pair ? half : 0;
    int kend = pair ? len : half;
    int idx = sub * 64 + lane;     // 0..127
    int t0 = idx;                  // query slot 0: queries 0..127
    int t1 = 128 + idx;            // query slot 1: queries 128..255 (cap len)
    const float scale = 0.23570226039551587f;  // 1/sqrt(18); folded into q
    float q[2][18], acc[2][18], l[2];
#pragma unroll
    for (int j = 0; j < 2; ++j) {
        l[j] = 0.f;
#pragma unroll
        for (int d = 0; d < 18; ++d) { q[j][d] = 0.f; acc[j][d] = 0.f; }
    }
    if (t0 < len) {
        const float* qp = qkv + ((size_t)t0 * BB + b) * 216 + hh * 18;
#pragma unroll
        for (int d = 0; d < 18; ++d) q[0][d] = qp[d] * scale;
    }
    int ns = (len > 128) ? 2 : 1;  // block-uniform slot count
    if (ns == 2 && t1 < len) {
        const float* qp = qkv + ((size_t)t1 * BB + b) * 216 + hh * 18;
#pragma unroll
        for (int d = 0; d < 18; ++d) q[1][d] = qp[d] * scale;
    }
    if (ns == 2) attn_core<2>(KV, q, acc, l, kbeg, kend);
    else         attn_core<1>(KV, q, acc, l, kbeg, kend);
    if (pair == 1) {  // publish partials
#pragma unroll
        for (int j = 0; j < 2; ++j) {
            if (j < ns) {
                pL[j][idx] = l[j];
#pragma unroll
                for (int d = 0; d < 18; ++d) pA[j][idx][d] = acc[j][d];
            }
        }
    }
    __syncthreads();
    if (pair == 0) {  // combine + store
        if (t0 < len) {
            float inv = 1.0f / (l[0] + pL[0][idx]);
            float* cb = ctx + ((size_t)t0 * BB + b) * 72 + hh * 18;
#pragma unroll
            for (int d = 0; d < 18; ++d) cb[d] = (acc[0][d] + pA[0][idx][d]) * inv;
        }
        if (ns == 2 && t1 < len) {
            float inv = 1.0f / (l[1] + pL[1][idx]);
            float* cb = ctx + ((size_t)t1 * BB + b) * 72 + hh * 18;
#pragma unroll
            for (int d = 0; d < 18; ++d) cb[d] = (acc[1][d] + pA[1][idx][d]) * inv;
        }
    }
}

// ---------------------------------------------------------------- h = LN(h + ctx@Wout.T+b) ; MFMA split-bf16
__global__ __launch_bounds__(256, 1) void k_outln(const float* __restrict__ ctx,
                                                  const unsigned short* __restrict__ Ohi,
                                                  const unsigned short* __restrict__ Olo,
                                                  const float* __restrict__ bias,
                                                  const float* __restrict__ g,
                                                  const float* __restrict__ beta,
                                                  float* __restrict__ h) {
    int tid = threadIdx.x;
    int w = tid >> 6;
    int lane = tid & 63;
    int n16 = lane & 15;
    int quad = lane >> 4;
    int m0 = blockIdx.x * 64 + w * 16;
    int r = m0 + n16;
    short8 Ahi[3], Alo[3];
#pragma unroll
    for (int s = 0; s < 3; ++s) {
        int k0 = s * 32 + quad * 8;
        float v[8];
        if (k0 < 72) {
            const float4* ap = (const float4*)(ctx + (size_t)r * 72 + k0);
            float4 v0 = ap[0], v1 = ap[1];
            v[0] = v0.x; v[1] = v0.y; v[2] = v0.z; v[3] = v0.w;
            v[4] = v1.x; v[5] = v1.y; v[6] = v1.z; v[7] = v1.w;
        } else {
#pragma unroll
            for (int j = 0; j < 8; ++j) v[j] = 0.f;
        }
        short8 ph, pl;
#pragma unroll
        for (int j = 0; j < 8; ++j) {
            unsigned short hi = f2bf_rn(v[j]);
            ph[j] = (short)hi;
            pl[j] = (short)f2bf_rn(v[j] - bf2f(hi));
        }
        Ahi[s] = ph; Alo[s] = pl;
    }
    f32x4 acc[5];
#pragma unroll
    for (int t = 0; t < 5; ++t) acc[t] = (f32x4){0.f, 0.f, 0.f, 0.f};
#pragma unroll
    for (int t = 0; t < 5; ++t) {
        int o = t * 16 + n16;
        int oc = (o > 71) ? 71 : o;
        const short8* bh = (const short8*)(Ohi + (size_t)oc * 96);
        const short8* bl = (const short8*)(Olo + (size_t)oc * 96);
        f32x4 a = acc[t];
#pragma unroll
        for (int s = 0; s < 3; ++s) {
            short8 Bh = bh[s * 4 + quad];
            short8 Bl = bl[s * 4 + quad];
            a = __builtin_amdgcn_mfma_f32_16x16x32_bf16(Ahi[s], Bh, a, 0, 0, 0);
            a = __builtin_amdgcn_mfma_f32_16x16x32_bf16(Ahi[s], Bl, a, 0, 0, 0);
            a = __builtin_amdgcn_mfma_f32_16x16x32_bf16(Alo[s], Bh, a, 0, 0, 0);
        }
        acc[t] = a;
    }
    float vals[5][4];
#pragma unroll
    for (int t = 0; t < 5; ++t) {
        int o = t * 16 + n16;
        bool valid = (o < 72);
        float bb = valid ? bias[o] : 0.f;
#pragma unroll
        for (int reg = 0; reg < 4; ++reg) {
            int row = m0 + quad * 4 + reg;
            float hv = valid ? h[(size_t)row * 72 + o] : 0.f;
            vals[t][reg] = acc[t][reg] + bb + hv;
        }
    }
#pragma unroll
    for (int reg = 0; reg < 4; ++reg) {
        float s = 0.f, q = 0.f;
#pragma unroll
        for (int t = 0; t < 5; ++t) {
            int o = t * 16 + n16;
            if (o < 72) { s += vals[t][reg]; q = fmaf(vals[t][reg], vals[t][reg], q); }
        }
#pragma unroll
        for (int m = 1; m < 16; m <<= 1) { s += __shfl_xor(s, m); q += __shfl_xor(q, m); }
        float mu = s / 72.0f;
        float var = fmaxf(q / 72.0f - mu * mu, 0.0f);
        float rstd = 1.0f / sqrtf(var + 1e-5f);
        int row = m0 + quad * 4 + reg;
#pragma unroll
        for (int t = 0; t < 5; ++t) {
            int o = t * 16 + n16;
            if (o < 72)
                h[(size_t)row * 72 + o] = (vals[t][reg] - mu) * rstd * g[o] + beta[o];
        }
    }
}

// ---------------------------------------------------------------- h = LN(h + relu(h@ff1.T)@ff2.T+b) ; MFMA split-bf16
__global__ __launch_bounds__(256, 1) void k_ffln(const unsigned short* __restrict__ F1hi,
                                                 const unsigned short* __restrict__ F1lo,
                                                 const float* __restrict__ b1,
                                                 const unsigned short* __restrict__ F2hi,
                                                 const unsigned short* __restrict__ F2lo,
                                                 const float* __restrict__ b2,
                                                 const float* __restrict__ g,
                                                 const float* __restrict__ beta,
                                                 float* __restrict__ h) {
    __shared__ float hid[64][129];
    int tid = threadIdx.x;
    int w = tid >> 6;
    int lane = tid & 63;
    int n16 = lane & 15;
    int quad = lane >> 4;
    int m0 = blockIdx.x * 64 + w * 16;
    int r = m0 + n16;
    short8 Ahi[3], Alo[3];
#pragma unroll
    for (int s = 0; s < 3; ++s) {
        int k0 = s * 32 + quad * 8;
        float v[8];
        if (k0 < 72) {
            const float4* ap = (const float4*)(h + (size_t)r * 72 + k0);
            float4 v0 = ap[0], v1 = ap[1];
            v[0] = v0.x; v[1] = v0.y; v[2] = v0.z; v[3] = v0.w;
            v[4] = v1.x; v[5] = v1.y; v[6] = v1.z; v[7] = v1.w;
        } else {
#pragma unroll
            for (int j = 0; j < 8; ++j) v[j] = 0.f;
        }
        short8 ph, pl;
#pragma unroll
        for (int j = 0; j < 8; ++j) {
            unsigned short hi = f2bf_rn(v[j]);
            ph[j] = (short)hi;
            pl[j] = (short)f2bf_rn(v[j] - bf2f(hi));
        }
        Ahi[s] = ph; Alo[s] = pl;
    }
#pragma unroll
    for (int t = 0; t < 8; ++t) {
        int j = t * 16 + n16;
        const short8* bh = (const short8*)(F1hi + (size_t)j * 96);
        const short8* bl = (const short8*)(F1lo + (size_t)j * 96);
        f32x4 a = (f32x4){0.f, 0.f, 0.f, 0.f};
#pragma unroll
        for (int s = 0; s < 3; ++s) {
            short8 Bh = bh[s * 4 + quad];
            short8 Bl = bl[s * 4 + quad];
            a = __builtin_amdgcn_mfma_f32_16x16x32_bf16(Ahi[s], Bh, a, 0, 0, 0);
            a = __builtin_amdgcn_mfma_f32_16x16x32_bf16(Ahi[s], Bl, a, 0, 0, 0);
            a = __builtin_amdgcn_mfma_f32_16x16x32_bf16(Alo[s], Bh, a, 0, 0, 0);
        }
        float bb = b1[j];
#pragma unroll
        for (int reg = 0; reg < 4; ++reg)
            hid[w * 16 + quad * 4 + reg][j] = fmaxf(a[reg] + bb, 0.f);
    }
    // wave-private rows: in-wave lgkmcnt ordering suffices, no barrier
    short8 A2hi[4], A2lo[4];
#pragma unroll
    for (int s = 0; s < 4; ++s) {
        const float* hp = &hid[w * 16 + n16][s * 32 + quad * 8];
        short8 ph, pl;
#pragma unroll
        for (int j = 0; j < 8; ++j) {
            float v = hp[j];
            unsigned short hi = f2bf_rn(v);
            ph[j] = (short)hi;
            pl[j] = (short)f2bf_rn(v - bf2f(hi));
        }
        A2hi[s] = ph; A2lo[s] = pl;
    }
    f32x4 acc[5];
#pragma unroll
    for (int t = 0; t < 5; ++t) acc[t] = (f32x4){0.f, 0.f, 0.f, 0.f};
#pragma unroll
    for (int t = 0; t < 5; ++t) {
        int o = t * 16 + n16;
        int oc = (o > 71) ? 71 : o;
        const short8* bh = (const short8*)(F2hi + (size_t)oc * 128);
        const short8* bl = (const short8*)(F2lo + (size_t)oc * 128);
        f32x4 a = acc[t];
#pragma unroll
        for (int s = 0; s < 4; ++s) {
            short8 Bh = bh[s * 4 + quad];
            short8 Bl = bl[s * 4 + quad];
            a = __builtin_amdgcn_mfma_f32_16x16x32_bf16(A2hi[s], Bh, a, 0, 0, 0);
            a = __builtin_amdgcn_mfma_f32_16x16x32_bf16(A2hi[s], Bl, a, 0, 0, 0);
            a = __builtin_amdgcn_mfma_f32_16x16x32_bf16(A2lo[s], Bh, a, 0, 0, 0);
        }
        acc[t] = a;
    }
    float vals[5][4];
#pragma unroll
    for (int t = 0; t < 5; ++t) {
        int o = t * 16 + n16;
        bool valid = (o < 72);
        float bb = valid ? b2[o] : 0.f;
#pragma unroll
        for (int reg = 0; reg < 4; ++reg) {
            int row = m0 + quad * 4 + reg;
            float hv = valid ? h[(size_t)row * 72 + o] : 0.f;
            vals[t][reg] = acc[t][reg] + bb + hv;
        }
    }
#pragma unroll
    for (int reg = 0; reg < 4; ++reg) {
        float s = 0.f, q = 0.f;
#pragma unroll
        for (int t = 0; t < 5; ++t) {
            int o = t * 16 + n16;
            if (o < 72) { s += vals[t][reg]; q = fmaf(vals[t][reg], vals[t][reg], q); }
        }
#pragma unroll
        for (int m = 1; m < 16; m <<= 1) { s += __shfl_xor(s, m); q += __shfl_xor(q, m); }
        float mu = s / 72.0f;
        float var = fmaxf(q / 72.0f - mu * mu, 0.0f);
        float rstd = 1.0f / sqrtf(var + 1e-5f);
        int row = m0 + quad * 4 + reg;
#pragma unroll
        for (int t = 0; t < 5; ++t) {
            int o = t * 16 + n16;
            if (o < 72)
                h[(size_t)row * 72 + o] = (vals[t][reg] - mu) * rstd * g[o] + beta[o];
        }
    }
}

// ---------------------------------------------------------------- masked mean-pool + static emb + 2-layer MLP
__global__ void k_head(const float* __restrict__ h, const int* __restrict__ lengths,
                       const float* __restrict__ statics, const float* __restrict__ W_emb,
                       const float* __restrict__ b_emb, const float* __restrict__ w1,
                       const float* __restrict__ bb1, const float* __restrict__ w2,
                       const float* __restrict__ bb2, float* __restrict__ out) {
    __shared__ float ps2[4][72];
    __shared__ float feat[108];
    __shared__ float hidm[108];
    __shared__ float st[9];
    int b = blockIdx.x, tid = threadIdx.x;
    int w = tid >> 6, lane = tid & 63;
    int len = lengths[b];
    if (tid < 9) st[tid] = statics[b * 9 + tid];
    for (int idx = tid; idx < 288; idx += 256) ((float*)ps2)[idx] = 0.f;
    __syncthreads();
#pragma unroll
    for (int c0 = 0; c0 < 128; c0 += 64) {
        int col = c0 + lane;
        if (col < 72) {
            float s = 0.f;
            for (int t = w; t < len; t += 4) s += h[((size_t)t * BB + b) * 72 + col];
            ps2[w][col] = s;
        }
    }
    __syncthreads();
    if (tid < 72)
        feat[tid] = (ps2[0][tid] + ps2[1][tid] + ps2[2][tid] + ps2[3][tid]) / ((float)len + 1.0f);
    if (tid >= 128 && tid < 164) {
        int o = tid - 128;
        float a = b_emb[o];
#pragma unroll
        for (int i = 0; i < 9; ++i) a = fmaf(st[i], W_emb[o * 9 + i], a);
        feat[72 + o] = a;
    }
    __syncthreads();
    if (tid < 108) {
        float a = bb1[tid];
        for (int i = 0; i < 108; ++i) a = fmaf(feat[i], w1[tid * 108 + i], a);
        hidm[tid] = fmaxf(a, 0.f);
    }
    __syncthreads();
    if (tid < 2) {
        float a = bb2[tid];
        for (int i = 0; i < 108; ++i) a = fmaf(hidm[i], w2[tid * 108 + i], a);
        out[b * 2 + tid] = a;
    }
}

// ---------------------------------------------------------------- final distance reduce
__global__ void k_dist(const float* __restrict__ rowsum, float* __restrict__ out) {
    __shared__ float red[256];
    int tid = threadIdx.x;
    red[tid] = rowsum[tid];
    __syncthreads();
    for (int s = 128; s > 0; s >>= 1) { if (tid < s) red[tid] += red[tid + s]; __syncthreads(); }
    if (tid == 0) out[2 * BB] = red[0] / 65536.0f;
}

extern "C" void kernel_launch(void* const* d_in, const int* in_sizes, int n_in,
                              void* d_out, int out_size, void* d_ws, size_t ws_size,
                              hipStream_t stream) {
    const float* src     = (const float*)d_in[0];
    const float* statics = (const float*)d_in[1];
    const float* times   = (const float*)d_in[2];
    const int*   lengths = (const int*)d_in[3];
    const float* W_enc = (const float*)d_in[4];  const float* b_enc = (const float*)d_in[5];
    const float* W_emb = (const float*)d_in[6];  const float* b_emb = (const float*)d_in[7];
    const float* Wq = (const float*)d_in[8];     const float* bq = (const float*)d_in[9];
    const float* Wk = (const float*)d_in[10];    const float* bk = (const float*)d_in[11];
    const float* Wv = (const float*)d_in[12];    const float* bv = (const float*)d_in[13];
    const float* Wskip = (const float*)d_in[14]; const float* bskip = (const float*)d_in[15];
    const float* enc_in_w = (const float*)d_in[16];  const float* enc_in_b = (const float*)d_in[17];
    const float* enc_out_w = (const float*)d_in[18]; const float* enc_out_b = (const float*)d_in[19];
    const float* ff1_w = (const float*)d_in[20]; const float* ff1_b = (const float*)d_in[21];
    const float* ff2_w = (const float*)d_in[22]; const float* ff2_b = (const float*)d_in[23];
    const float* ln1_g = (const float*)d_in[24]; const float* ln1_b = (const float*)d_in[25];
    const float* ln2_g = (const float*)d_in[26]; const float* ln2_b = (const float*)d_in[27];
    const float* w1 = (const float*)d_in[28];    const float* bb1 = (const float*)d_in[29];
    const float* w2 = (const float*)d_in[30];    const float* bb2 = (const float*)d_in[31];
    float* out = (float*)d_out;

    float* p = (float*)d_ws;
    float* x    = p; p += (size_t)ROWS * 36;
    float* h    = p; p += (size_t)ROWS * 72;
    float* qkv  = p; p += (size_t)ROWS * 216;
    float* ctx  = p; p += (size_t)ROWS * 72;
    float* qg   = p; p += (size_t)36 * BB * 36;
    float* kg   = p; p += (size_t)36 * BB * 36;
    float* vg   = p; p += (size_t)36 * BB * 36;
    float* Abuf = p; p += (size_t)BB * 1296;
    float* sqv  = p; p += BB;
    float* rsum = p; p += BB;
    float* ts   = p; p += 32;
    unsigned short* Whi  = (unsigned short*)p; p += (2 * 216 * 96) / 2;
    unsigned short* Wlo  = (unsigned short*)p; p += (2 * 216 * 96) / 2;
    unsigned short* F1hi = (unsigned short*)p; p += (2 * 128 * 96) / 2;
    unsigned short* F1lo = (unsigned short*)p; p += (2 * 128 * 96) / 2;
    unsigned short* F2hi = (unsigned short*)p; p += (2 * 72 * 128) / 2;
    unsigned short* F2lo = (unsigned short*)p; p += (2 * 72 * 128) / 2;
    unsigned short* Ohi  = (unsigned short*)p; p += (2 * 72 * 96) / 2;
    unsigned short* Olo  = (unsigned short*)p; p += (2 * 72 * 96) / 2;

    k_prep<<<162, 256, 0, stream>>>(enc_in_w, ff1_w, ff2_w, enc_out_w,
                                    Whi, Wlo, F1hi, F1lo, F2hi, F2lo, Ohi, Olo, ts);
    k_enc1<<<dim3(TT, 4), 256, 0, stream>>>(src, W_enc, b_enc, x);
    k_enc2<<<dim3(TT, 4), 256, 0, stream>>>(x, Wskip, bskip, h);
    k_pe<<<(ROWS * 36) / 256, 256, 0, stream>>>(times, ts, h);
    k_graph_qkv<<<dim3(36, 12), 256, 0, stream>>>(x, Wq, bq, Wk, bk, Wv, bv, qg, kg, vg);
    k_graph_attn<<<BB, 128, 0, stream>>>(qg, kg, vg, h, Abuf, sqv);
    k_gram<<<BB, 256, 0, stream>>>(Abuf, sqv, rsum);
    for (int l = 0; l < 2; ++l) {
        k_qkv<<<ROWS / 64, 256, 0, stream>>>(h, Whi + (size_t)l * 216 * 96,
                                             Wlo + (size_t)l * 216 * 96,
                                             enc_in_b + l * 216, qkv);
        k_attn<<<BB * 4, 256, 0, stream>>>(qkv, lengths, ctx);
        k_outln<<<ROWS / 64, 256, 0, stream>>>(ctx, Ohi + (size_t)l * 72 * 96,
                                               Olo + (size_t)l * 72 * 96, enc_out_b + l * 72,
                                               ln1_g + l * 72, ln1_b + l * 72, h);
        k_ffln<<<ROWS / 64, 256, 0, stream>>>(F1hi + (size_t)l * 128 * 96,
                                              F1lo + (size_t)l * 128 * 96, ff1_b + l * 128,
                                              F2hi + (size_t)l * 72 * 128,
                                              F2lo + (size_t)l * 72 * 128, ff2_b + l * 72,
                                              ln2_g + l * 72, ln2_b + l * 72, h);
    }
    k_head<<<BB, 256, 0, stream>>>(h, lengths, statics, W_emb, b_emb, w1, bb1, w2, bb2, out);
    k_dist<<<1, 256, 0, stream>>>(rsum, out);
}

// Round 15
// 500.326 us; speedup vs baseline: 1.2159x; 1.2159x over previous
//
#include <hip/hip_runtime.h>

#define TT 215
#define BB 256
#define ROWS (TT * BB)  // 55040 = 860 * 64

typedef __attribute__((ext_vector_type(8))) short short8;   // 8 bf16 = 4 VGPRs
typedef __attribute__((ext_vector_type(4))) float f32x4;    // MFMA acc

__device__ __forceinline__ unsigned short f2bf_rn(float x) {
    unsigned int u = __float_as_uint(x);
    u = u + 0x7FFFu + ((u >> 16) & 1u);   // round-to-nearest-even bf16
    return (unsigned short)(u >> 16);
}
__device__ __forceinline__ float bf2f(unsigned short b) {
    return __uint_as_float(((unsigned int)b) << 16);
}

// ---------------------------------------------------------------- one-shot prep: timescales + split-bf16 weights
// enc_in [2][216][96], ff1 [2][128][96], ff2 [2][72][128], Wout [2][72][96]
__global__ void k_prep(const float* __restrict__ enc_in_w, const float* __restrict__ ff1_w,
                       const float* __restrict__ ff2_w, const float* __restrict__ enc_out_w,
                       unsigned short* __restrict__ Whi, unsigned short* __restrict__ Wlo,
                       unsigned short* __restrict__ F1hi, unsigned short* __restrict__ F1lo,
                       unsigned short* __restrict__ F2hi, unsigned short* __restrict__ F2lo,
                       unsigned short* __restrict__ Ohi, unsigned short* __restrict__ Olo,
                       float* __restrict__ ts) {
    int g = blockIdx.x * 256 + threadIdx.x;
    if (g < 18) ts[g] = (float)pow(215.0, (double)g / 17.0);  // matches np float64 215**linspace
    if (g < 2 * 216 * 96) {
        int l = g / (216 * 96), rem = g % (216 * 96);
        int o = rem / 96, k = rem % 96;
        float v = (k < 72) ? enc_in_w[((size_t)l * 216 + o) * 72 + k] : 0.f;
        unsigned short hi = f2bf_rn(v);
        Whi[g] = hi; Wlo[g] = f2bf_rn(v - bf2f(hi));
    }
    if (g < 2 * 128 * 96) {
        int l = g / (128 * 96), rem = g % (128 * 96);
        int j = rem / 96, k = rem % 96;
        float v = (k < 72) ? ff1_w[((size_t)l * 128 + j) * 72 + k] : 0.f;
        unsigned short hi = f2bf_rn(v);
        F1hi[g] = hi; F1lo[g] = f2bf_rn(v - bf2f(hi));
    }
    if (g < 2 * 72 * 128) {  // ff2 already [o][j] = B[n][k], K=128
        float v = ff2_w[g];
        unsigned short hi = f2bf_rn(v);
        F2hi[g] = hi; F2lo[g] = f2bf_rn(v - bf2f(hi));
    }
    if (g < 2 * 72 * 96) {
        int l = g / (72 * 96), rem = g % (72 * 96);
        int o = rem / 96, k = rem % 96;
        float v = (k < 72) ? enc_out_w[((size_t)l * 72 + o) * 72 + k] : 0.f;
        unsigned short hi = f2bf_rn(v);
        Ohi[g] = hi; Olo[g] = f2bf_rn(v - bf2f(hi));
    }
}

// ---------------------------------------------------------------- x = (src[:,:,:36] @ W_enc.T + b)*6 ; grid (215,4)
__global__ __launch_bounds__(256, 1) void k_enc1(const float* __restrict__ src,
                                                 const float* __restrict__ W,
                                                 const float* __restrict__ bias,
                                                 float* __restrict__ x) {
    int row = blockIdx.x * 256 + threadIdx.x;
    int o0 = blockIdx.y * 9;
    float s[36];
    const float4* sv = (const float4*)(src + (size_t)row * 72);
#pragma unroll
    for (int k = 0; k < 9; ++k) {
        float4 v = sv[k];
        s[4 * k] = v.x; s[4 * k + 1] = v.y; s[4 * k + 2] = v.z; s[4 * k + 3] = v.w;
    }
    float* xp = x + (size_t)row * 36 + o0;
#pragma unroll
    for (int o = 0; o < 9; ++o) {
        float a = bias[o0 + o];
        const float* w = W + (size_t)(o0 + o) * 36;
#pragma unroll
        for (int i = 0; i < 36; ++i) a = fmaf(s[i], w[i], a);
        xp[o] = a * 6.0f;
    }
}

// ---------------------------------------------------------------- h[:,:, :36] = x @ Wskip.T + b ; grid (215,4)
__global__ __launch_bounds__(256, 1) void k_enc2(const float* __restrict__ x,
                                                 const float* __restrict__ W,
                                                 const float* __restrict__ bias,
                                                 float* __restrict__ h) {
    int row = blockIdx.x * 256 + threadIdx.x;
    int o0 = blockIdx.y * 9;
    float xr[36];
    const float4* xv = (const float4*)(x + (size_t)row * 36);
#pragma unroll
    for (int k = 0; k < 9; ++k) {
        float4 v = xv[k];
        xr[4 * k] = v.x; xr[4 * k + 1] = v.y; xr[4 * k + 2] = v.z; xr[4 * k + 3] = v.w;
    }
    float* hp = h + (size_t)row * 72 + o0;
#pragma unroll
    for (int o = 0; o < 9; ++o) {
        float a = bias[o0 + o];
        const float* w = W + (size_t)(o0 + o) * 36;
#pragma unroll
        for (int i = 0; i < 36; ++i) a = fmaf(xr[i], w[i], a);
        hp[o] = a;
    }
}

// ---------------------------------------------------------------- h[:,:,36:] = pe ; elementwise
__global__ __launch_bounds__(256) void k_pe(const float* __restrict__ times,
                                            const float* __restrict__ ts,
                                            float* __restrict__ h) {
    int idx = blockIdx.x * 256 + threadIdx.x;  // < ROWS*36
    int d = idx % 36, row = idx / 36;
    float t = times[row];
    float val;
    if (d < 18) val = sinf(t / ts[d]);
    else        val = cosf(t / ts[d - 18]);
    h[(size_t)row * 72 + 36 + d] = val;
}

// ---------------------------------------------------------------- graph q|k|v ; grid (36, 12): mat = y>>2, o0 = (y&3)*9
__global__ __launch_bounds__(256, 1) void k_graph_qkv(const float* __restrict__ x,
                                                      const float* __restrict__ Wq, const float* __restrict__ bq,
                                                      const float* __restrict__ Wk, const float* __restrict__ bk,
                                                      const float* __restrict__ Wv, const float* __restrict__ bv,
                                                      float* __restrict__ qg, float* __restrict__ kg,
                                                      float* __restrict__ vg) {
    int row = blockIdx.x * 256 + threadIdx.x;  // < 9216
    int mat = blockIdx.y >> 2;
    int o0 = (blockIdx.y & 3) * 9;
    const float* W; const float* bias; float* out;
    if (mat == 0)      { W = Wq; bias = bq; out = qg; }
    else if (mat == 1) { W = Wk; bias = bk; out = kg; }
    else               { W = Wv; bias = bv; out = vg; }
    float xr[36];
    const float4* xv = (const float4*)(x + (size_t)row * 36);
#pragma unroll
    for (int k = 0; k < 9; ++k) {
        float4 v = xv[k];
        xr[4 * k] = v.x; xr[4 * k + 1] = v.y; xr[4 * k + 2] = v.z; xr[4 * k + 3] = v.w;
    }
    float* op = out + (size_t)row * 36 + o0;
#pragma unroll
    for (int o = 0; o < 9; ++o) {
        float a = bias[o0 + o];
        const float* w = W + (size_t)(o0 + o) * 36;
#pragma unroll
        for (int i = 0; i < 36; ++i) a = fmaf(xr[i], w[i], a);
        op[o] = a;
    }
}

// ---------------------------------------------------------------- graph attention per batch; h[:36,:,:36] += msg
__global__ void k_graph_attn(const float* __restrict__ qg, const float* __restrict__ kg,
                             const float* __restrict__ vg, float* __restrict__ h,
                             float* __restrict__ Abuf, float* __restrict__ sqv) {
    __shared__ float q[1296], k[1296], v[1296], A[1296];
    __shared__ float red[128];
    int b = blockIdx.x, tid = threadIdx.x;
    for (int i = tid; i < 1296; i += 128) {
        int t = i / 36, e = i % 36;
        int g = (t * BB + b) * 36 + e;
        q[i] = qg[g]; k[i] = kg[g]; v[i] = vg[g];
    }
    __syncthreads();
    for (int i = tid; i < 1296; i += 128) {
        int r = i / 36, c = i % 36;
        float a = 0.f;
#pragma unroll
        for (int e = 0; e < 36; ++e) a = fmaf(q[r * 36 + e], k[c * 36 + e], a);
        A[i] = a * (1.0f / 6.0f);
    }
    __syncthreads();
    if (tid < 36) {
        float m = -1e30f;
        for (int j = 0; j < 36; ++j) m = fmaxf(m, A[tid * 36 + j]);
        float s = 0.f;
        for (int j = 0; j < 36; ++j) { float e = expf(A[tid * 36 + j] - m); A[tid * 36 + j] = e; s += e; }
        float inv = 1.0f / s;
        for (int j = 0; j < 36; ++j) A[tid * 36 + j] *= inv;
    }
    __syncthreads();
    float lsq = 0.f;
    for (int i = tid; i < 1296; i += 128) {
        float a = A[i];
        Abuf[(size_t)b * 1296 + i] = a;
        lsq = fmaf(a, a, lsq);
        int r = i / 36, e = i % 36;
        float m = 0.f;
#pragma unroll
        for (int j = 0; j < 36; ++j) m = fmaf(A[r * 36 + j], v[j * 36 + e], m);
        h[((size_t)r * BB + b) * 72 + e] += m;
    }
    red[tid] = lsq;
    __syncthreads();
    for (int s = 64; s > 0; s >>= 1) { if (tid < s) red[tid] += red[tid + s]; __syncthreads(); }
    if (tid == 0) sqv[b] = red[0];
}

// ---------------------------------------------------------------- Gram row + per-row distance partial sum
__global__ void k_gram(const float* __restrict__ Abuf, const float* __restrict__ sqv,
                       float* __restrict__ rowsum) {
    __shared__ float Arow[1296];
    __shared__ float red[256];
    int b1 = blockIdx.x, tid = threadIdx.x;
    for (int i = tid; i < 1296; i += 256) Arow[i] = Abuf[(size_t)b1 * 1296 + i];
    __syncthreads();
    int b2 = tid;
    const float* a2 = Abuf + (size_t)b2 * 1296;
    float dot = 0.f;
    for (int e = 0; e < 1296; ++e) dot = fmaf(Arow[e], a2[e], dot);
    float d2 = fmaxf(sqv[b1] + sqv[b2] - 2.0f * dot, 0.0f);
    red[tid] = (d2 > 0.0f) ? sqrtf(d2) : 0.0f;
    __syncthreads();
    for (int s = 128; s > 0; s >>= 1) { if (tid < s) red[tid] += red[tid + s]; __syncthreads(); }
    if (tid == 0) rowsum[b1] = red[0];
}

// ---------------------------------------------------------------- qkv = h @ W_in.T + b ; MFMA split-bf16
__global__ __launch_bounds__(256, 1) void k_qkv(const float* __restrict__ h,
                                                const unsigned short* __restrict__ Whi,
                                                const unsigned short* __restrict__ Wlo,
                                                const float* __restrict__ bias,
                                                float* __restrict__ qkv) {
    int tid = threadIdx.x;
    int w = tid >> 6;
    int lane = tid & 63;
    int n16 = lane & 15;
    int quad = lane >> 4;
    int m0 = blockIdx.x * 64 + w * 16;
    int r = m0 + n16;
    short8 Ahi[3], Alo[3];
#pragma unroll
    for (int s = 0; s < 3; ++s) {
        int k0 = s * 32 + quad * 8;
        float v[8];
        if (k0 < 72) {
            const float4* ap = (const float4*)(h + (size_t)r * 72 + k0);
            float4 v0 = ap[0], v1 = ap[1];
            v[0] = v0.x; v[1] = v0.y; v[2] = v0.z; v[3] = v0.w;
            v[4] = v1.x; v[5] = v1.y; v[6] = v1.z; v[7] = v1.w;
        } else {
#pragma unroll
            for (int j = 0; j < 8; ++j) v[j] = 0.f;
        }
        short8 ph, pl;
#pragma unroll
        for (int j = 0; j < 8; ++j) {
            unsigned short hi = f2bf_rn(v[j]);
            ph[j] = (short)hi;
            pl[j] = (short)f2bf_rn(v[j] - bf2f(hi));
        }
        Ahi[s] = ph; Alo[s] = pl;
    }
    f32x4 acc[14];
#pragma unroll
    for (int t = 0; t < 14; ++t) acc[t] = (f32x4){0.f, 0.f, 0.f, 0.f};
#pragma unroll
    for (int t = 0; t < 14; ++t) {
        int o = t * 16 + n16;
        int oc = (o > 215) ? 215 : o;
        const short8* bh = (const short8*)(Whi + (size_t)oc * 96);
        const short8* bl = (const short8*)(Wlo + (size_t)oc * 96);
        f32x4 a = acc[t];
#pragma unroll
        for (int s = 0; s < 3; ++s) {
            short8 Bh = bh[s * 4 + quad];
            short8 Bl = bl[s * 4 + quad];
            a = __builtin_amdgcn_mfma_f32_16x16x32_bf16(Ahi[s], Bh, a, 0, 0, 0);
            a = __builtin_amdgcn_mfma_f32_16x16x32_bf16(Ahi[s], Bl, a, 0, 0, 0);
            a = __builtin_amdgcn_mfma_f32_16x16x32_bf16(Alo[s], Bh, a, 0, 0, 0);
        }
        acc[t] = a;
    }
#pragma unroll
    for (int t = 0; t < 14; ++t) {
        int col = t * 16 + n16;
        if (col < 216) {
            float b = bias[col];
#pragma unroll
            for (int reg = 0; reg < 4; ++reg) {
                int row = m0 + quad * 4 + reg;
                qkv[(size_t)row * 216 + col] = acc[t][reg] + b;
            }
        }
    }
}

// ---------------------------------------------------------------- masked MHA v6: MFMA flash per (b,head)
// 16-query strips per wave. QK^T: Q split-bf16 (2 MFMA/tile), K bf16 in LDS
// [key][40]. exp+mask in C-layout regs; P bf16 -> wave-private LDS [16][232]
// -> A-layout; PV with V^T bf16 [32][232]. l rides C-layout rows, reduced
// via 16-lane shuffles. All LDS strides 16B-aligned, 2-way-bank-safe.
__global__ __launch_bounds__(256, 1) void k_attn(const float* __restrict__ qkv,
                                                 const int* __restrict__ lengths,
                                                 float* __restrict__ ctx) {
    __shared__ __attribute__((aligned(16))) unsigned short Kb[215 * 40];   // [key][40], cols 18..39 zero
    __shared__ __attribute__((aligned(16))) unsigned short Vt[32 * 232];   // [d][232], rows 18..31 zero
    __shared__ __attribute__((aligned(16))) unsigned short Pw[4][16 * 232];// per-wave P strip
    int b = blockIdx.x & (BB - 1);
    int hh = blockIdx.x >> 8;
    int tid = threadIdx.x;
    int len = lengths[b];
    // zero K and V^T (pads + tails must be 0; garbage here -> NaN poison)
    for (int i = tid; i < (215 * 40) / 2; i += 256) ((unsigned int*)Kb)[i] = 0u;
    for (int i = tid; i < (32 * 232) / 2; i += 256) ((unsigned int*)Vt)[i] = 0u;
    __syncthreads();
    for (int i = tid; i < len * 18; i += 256) {
        int s = i / 18, d = i % 18;
        size_t base2 = ((size_t)s * BB + b) * 216 + hh * 18 + d;
        Kb[s * 40 + d] = f2bf_rn(qkv[base2 + 72]);
        Vt[d * 232 + s] = f2bf_rn(qkv[base2 + 144]);
    }
    __syncthreads();
    int w = tid >> 6;
    int lane = tid & 63;
    int n16 = lane & 15;
    int quad = lane >> 4;
    const float scale = 0.23570226039551587f;  // 1/sqrt(18); folded into Q
    int nk2 = (len + 31) >> 5;     // PV k-tiles (K=32)
    int nkt = nk2 * 2;             // QK n-tiles (16 keys each), padded to k2 granularity
    int nstrips = (len + 15) >> 4;
    unsigned short* P = &Pw[w][0];
    for (int strip = w; strip < nstrips; strip += 4) {
        int q0 = strip * 16;
        int qr = q0 + n16; if (qr > 214) qr = 214;
        // ---- Q A-frag (A[m=n16][k=quad*8+j]), scaled, split hi/lo
        float qv[8];
#pragma unroll
        for (int j = 0; j < 8; ++j) qv[j] = 0.f;
        {
            const float* qp = qkv + ((size_t)qr * BB + b) * 216 + hh * 18;
            int d0 = quad * 8;
            if (d0 < 16) {
                const float2* q2 = (const float2*)(qp + d0);
                float2 a0 = q2[0], a1 = q2[1], a2 = q2[2], a3 = q2[3];
                qv[0] = a0.x; qv[1] = a0.y; qv[2] = a1.x; qv[3] = a1.y;
                qv[4] = a2.x; qv[5] = a2.y; qv[6] = a3.x; qv[7] = a3.y;
            } else if (d0 == 16) {
                qv[0] = qp[16]; qv[1] = qp[17];
            }
        }
        short8 Qhi, Qlo;
#pragma unroll
        for (int j = 0; j < 8; ++j) {
            float v = qv[j] * scale;
            unsigned short hi = f2bf_rn(v);
            Qhi[j] = (short)hi;
            Qlo[j] = (short)f2bf_rn(v - bf2f(hi));
        }
        // ---- QK^T tiles -> exp -> P (LDS), accumulate row sums
        float lsum[4] = {0.f, 0.f, 0.f, 0.f};
        for (int kt = 0; kt < nkt; ++kt) {
            int key = kt * 16 + n16;
            int kr = (key > 214) ? 214 : key;
            short8 Bk = *(const short8*)(Kb + kr * 40 + quad * 8);
            f32x4 S = (f32x4){0.f, 0.f, 0.f, 0.f};
            S = __builtin_amdgcn_mfma_f32_16x16x32_bf16(Qlo, Bk, S, 0, 0, 0);
            S = __builtin_amdgcn_mfma_f32_16x16x32_bf16(Qhi, Bk, S, 0, 0, 0);
            // C-layout: col=n16 (key), row=quad*4+reg (query)
#pragma unroll
            for (int reg = 0; reg < 4; ++reg) {
                float p = (key < len) ? __expf(S[reg]) : 0.f;
                lsum[reg] += p;
                P[(quad * 4 + reg) * 232 + kt * 16 + n16] = f2bf_rn(p);
            }
        }
#pragma unroll
        for (int m = 1; m < 16; m <<= 1) {
#pragma unroll
            for (int reg = 0; reg < 4; ++reg) lsum[reg] += __shfl_xor(lsum[reg], m);
        }
        // ---- PV: A = P[m=n16 query][k=key], B = Vt[n=d][k=key]
        f32x4 o0 = (f32x4){0.f, 0.f, 0.f, 0.f};
        f32x4 o1 = (f32x4){0.f, 0.f, 0.f, 0.f};
        for (int k2 = 0; k2 < nk2; ++k2) {
            short8 Af = *(const short8*)(P + n16 * 232 + k2 * 32 + quad * 8);
            short8 Bv0 = *(const short8*)(Vt + n16 * 232 + k2 * 32 + quad * 8);
            short8 Bv1 = *(const short8*)(Vt + (16 + n16) * 232 + k2 * 32 + quad * 8);
            o0 = __builtin_amdgcn_mfma_f32_16x16x32_bf16(Af, Bv0, o0, 0, 0, 0);
            o1 = __builtin_amdgcn_mfma_f32_16x16x32_bf16(Af, Bv1, o1, 0, 0, 0);
        }
        // ---- store: C-layout col=n16 -> dim d, row=quad*4+reg -> query
#pragma unroll
        for (int reg = 0; reg < 4; ++reg) {
            int t = q0 + quad * 4 + reg;
            if (t < len) {
                float inv = 1.0f / lsum[reg];
                float* cb = ctx + ((size_t)t * BB + b) * 72 + hh * 18;
                cb[n16] = o0[reg] * inv;
                if (n16 < 2) cb[16 + n16] = o1[reg] * inv;
            }
        }
    }
}

// ---------------------------------------------------------------- h = LN(h + ctx@Wout.T+b) ; MFMA split-bf16
__global__ __launch_bounds__(256, 1) void k_outln(const float* __restrict__ ctx,
                                                  const unsigned short* __restrict__ Ohi,
                                                  const unsigned short* __restrict__ Olo,
                                                  const float* __restrict__ bias,
                                                  const float* __restrict__ g,
                                                  const float* __restrict__ beta,
                                                  float* __restrict__ h) {
    int tid = threadIdx.x;
    int w = tid >> 6;
    int lane = tid & 63;
    int n16 = lane & 15;
    int quad = lane >> 4;
    int m0 = blockIdx.x * 64 + w * 16;
    int r = m0 + n16;
    short8 Ahi[3], Alo[3];
#pragma unroll
    for (int s = 0; s < 3; ++s) {
        int k0 = s * 32 + quad * 8;
        float v[8];
        if (k0 < 72) {
            const float4* ap = (const float4*)(ctx + (size_t)r * 72 + k0);
            float4 v0 = ap[0], v1 = ap[1];
            v[0] = v0.x; v[1] = v0.y; v[2] = v0.z; v[3] = v0.w;
            v[4] = v1.x; v[5] = v1.y; v[6] = v1.z; v[7] = v1.w;
        } else {
#pragma unroll
            for (int j = 0; j < 8; ++j) v[j] = 0.f;
        }
        short8 ph, pl;
#pragma unroll
        for (int j = 0; j < 8; ++j) {
            unsigned short hi = f2bf_rn(v[j]);
            ph[j] = (short)hi;
            pl[j] = (short)f2bf_rn(v[j] - bf2f(hi));
        }
        Ahi[s] = ph; Alo[s] = pl;
    }
    f32x4 acc[5];
#pragma unroll
    for (int t = 0; t < 5; ++t) acc[t] = (f32x4){0.f, 0.f, 0.f, 0.f};
#pragma unroll
    for (int t = 0; t < 5; ++t) {
        int o = t * 16 + n16;
        int oc = (o > 71) ? 71 : o;
        const short8* bh = (const short8*)(Ohi + (size_t)oc * 96);
        const short8* bl = (const short8*)(Olo + (size_t)oc * 96);
        f32x4 a = acc[t];
#pragma unroll
        for (int s = 0; s < 3; ++s) {
            short8 Bh = bh[s * 4 + quad];
            short8 Bl = bl[s * 4 + quad];
            a = __builtin_amdgcn_mfma_f32_16x16x32_bf16(Ahi[s], Bh, a, 0, 0, 0);
            a = __builtin_amdgcn_mfma_f32_16x16x32_bf16(Ahi[s], Bl, a, 0, 0, 0);
            a = __builtin_amdgcn_mfma_f32_16x16x32_bf16(Alo[s], Bh, a, 0, 0, 0);
        }
        acc[t] = a;
    }
    float vals[5][4];
#pragma unroll
    for (int t = 0; t < 5; ++t) {
        int o = t * 16 + n16;
        bool valid = (o < 72);
        float bb = valid ? bias[o] : 0.f;
#pragma unroll
        for (int reg = 0; reg < 4; ++reg) {
            int row = m0 + quad * 4 + reg;
            float hv = valid ? h[(size_t)row * 72 + o] : 0.f;
            vals[t][reg] = acc[t][reg] + bb + hv;
        }
    }
#pragma unroll
    for (int reg = 0; reg < 4; ++reg) {
        float s = 0.f, q = 0.f;
#pragma unroll
        for (int t = 0; t < 5; ++t) {
            int o = t * 16 + n16;
            if (o < 72) { s += vals[t][reg]; q = fmaf(vals[t][reg], vals[t][reg], q); }
        }
#pragma unroll
        for (int m = 1; m < 16; m <<= 1) { s += __shfl_xor(s, m); q += __shfl_xor(q, m); }
        float mu = s / 72.0f;
        float var = fmaxf(q / 72.0f - mu * mu, 0.0f);
        float rstd = 1.0f / sqrtf(var + 1e-5f);
        int row = m0 + quad * 4 + reg;
#pragma unroll
        for (int t = 0; t < 5; ++t) {
            int o = t * 16 + n16;
            if (o < 72)
                h[(size_t)row * 72 + o] = (vals[t][reg] - mu) * rstd * g[o] + beta[o];
        }
    }
}

// ---------------------------------------------------------------- h = LN(h + relu(h@ff1.T)@ff2.T+b) ; MFMA split-bf16
__global__ __launch_bounds__(256, 1) void k_ffln(const unsigned short* __restrict__ F1hi,
                                                 const unsigned short* __restrict__ F1lo,
                                                 const float* __restrict__ b1,
                                                 const unsigned short* __restrict__ F2hi,
                                                 const unsigned short* __restrict__ F2lo,
                                                 const float* __restrict__ b2,
                                                 const float* __restrict__ g,
                                                 const float* __restrict__ beta,
                                                 float* __restrict__ h) {
    __shared__ float hid[64][129];
    int tid = threadIdx.x;
    int w = tid >> 6;
    int lane = tid & 63;
    int n16 = lane & 15;
    int quad = lane >> 4;
    int m0 = blockIdx.x * 64 + w * 16;
    int r = m0 + n16;
    short8 Ahi[3], Alo[3];
#pragma unroll
    for (int s = 0; s < 3; ++s) {
        int k0 = s * 32 + quad * 8;
        float v[8];
        if (k0 < 72) {
            const float4* ap = (const float4*)(h + (size_t)r * 72 + k0);
            float4 v0 = ap[0], v1 = ap[1];
            v[0] = v0.x; v[1] = v0.y; v[2] = v0.z; v[3] = v0.w;
            v[4] = v1.x; v[5] = v1.y; v[6] = v1.z; v[7] = v1.w;
        } else {
#pragma unroll
            for (int j = 0; j < 8; ++j) v[j] = 0.f;
        }
        short8 ph, pl;
#pragma unroll
        for (int j = 0; j < 8; ++j) {
            unsigned short hi = f2bf_rn(v[j]);
            ph[j] = (short)hi;
            pl[j] = (short)f2bf_rn(v[j] - bf2f(hi));
        }
        Ahi[s] = ph; Alo[s] = pl;
    }
#pragma unroll
    for (int t = 0; t < 8; ++t) {
        int j = t * 16 + n16;
        const short8* bh = (const short8*)(F1hi + (size_t)j * 96);
        const short8* bl = (const short8*)(F1lo + (size_t)j * 96);
        f32x4 a = (f32x4){0.f, 0.f, 0.f, 0.f};
#pragma unroll
        for (int s = 0; s < 3; ++s) {
            short8 Bh = bh[s * 4 + quad];
            short8 Bl = bl[s * 4 + quad];
            a = __builtin_amdgcn_mfma_f32_16x16x32_bf16(Ahi[s], Bh, a, 0, 0, 0);
            a = __builtin_amdgcn_mfma_f32_16x16x32_bf16(Ahi[s], Bl, a, 0, 0, 0);
            a = __builtin_amdgcn_mfma_f32_16x16x32_bf16(Alo[s], Bh, a, 0, 0, 0);
        }
        float bb = b1[j];
#pragma unroll
        for (int reg = 0; reg < 4; ++reg)
            hid[w * 16 + quad * 4 + reg][j] = fmaxf(a[reg] + bb, 0.f);
    }
    // wave-private rows: in-wave lgkmcnt ordering suffices, no barrier
    short8 A2hi[4], A2lo[4];
#pragma unroll
    for (int s = 0; s < 4; ++s) {
        const float* hp = &hid[w * 16 + n16][s * 32 + quad * 8];
        short8 ph, pl;
#pragma unroll
        for (int j = 0; j < 8; ++j) {
            float v = hp[j];
            unsigned short hi = f2bf_rn(v);
            ph[j] = (short)hi;
            pl[j] = (short)f2bf_rn(v - bf2f(hi));
        }
        A2hi[s] = ph; A2lo[s] = pl;
    }
    f32x4 acc[5];
#pragma unroll
    for (int t = 0; t < 5; ++t) acc[t] = (f32x4){0.f, 0.f, 0.f, 0.f};
#pragma unroll
    for (int t = 0; t < 5; ++t) {
        int o = t * 16 + n16;
        int oc = (o > 71) ? 71 : o;
        const short8* bh = (const short8*)(F2hi + (size_t)oc * 128);
        const short8* bl = (const short8*)(F2lo + (size_t)oc * 128);
        f32x4 a = acc[t];
#pragma unroll
        for (int s = 0; s < 4; ++s) {
            short8 Bh = bh[s * 4 + quad];
            short8 Bl = bl[s * 4 + quad];
            a = __builtin_amdgcn_mfma_f32_16x16x32_bf16(A2hi[s], Bh, a, 0, 0, 0);
            a = __builtin_amdgcn_mfma_f32_16x16x32_bf16(A2hi[s], Bl, a, 0, 0, 0);
            a = __builtin_amdgcn_mfma_f32_16x16x32_bf16(A2lo[s], Bh, a, 0, 0, 0);
        }
        acc[t] = a;
    }
    float vals[5][4];
#pragma unroll
    for (int t = 0; t < 5; ++t) {
        int o = t * 16 + n16;
        bool valid = (o < 72);
        float bb = valid ? b2[o] : 0.f;
#pragma unroll
        for (int reg = 0; reg < 4; ++reg) {
            int row = m0 + quad * 4 + reg;
            float hv = valid ? h[(size_t)row * 72 + o] : 0.f;
            vals[t][reg] = acc[t][reg] + bb + hv;
        }
    }
#pragma unroll
    for (int reg = 0; reg < 4; ++reg) {
        float s = 0.f, q = 0.f;
#pragma unroll
        for (int t = 0; t < 5; ++t) {
            int o = t * 16 + n16;
            if (o < 72) { s += vals[t][reg]; q = fmaf(vals[t][reg], vals[t][reg], q); }
        }
#pragma unroll
        for (int m = 1; m < 16; m <<= 1) { s += __shfl_xor(s, m); q += __shfl_xor(q, m); }
        float mu = s / 72.0f;
        float var = fmaxf(q / 72.0f - mu * mu, 0.0f);
        float rstd = 1.0f / sqrtf(var + 1e-5f);
        int row = m0 + quad * 4 + reg;
#pragma unroll
        for (int t = 0; t < 5; ++t) {
            int o = t * 16 + n16;
            if (o < 72)
                h[(size_t)row * 72 + o] = (vals[t][reg] - mu) * rstd * g[o] + beta[o];
        }
    }
}

// ---------------------------------------------------------------- masked mean-pool + static emb + 2-layer MLP
__global__ void k_head(const float* __restrict__ h, const int* __restrict__ lengths,
                       const float* __restrict__ statics, const float* __restrict__ W_emb,
                       const float* __restrict__ b_emb, const float* __restrict__ w1,
                       const float* __restrict__ bb1, const float* __restrict__ w2,
                       const float* __restrict__ bb2, float* __restrict__ out) {
    __shared__ float ps2[4][72];
    __shared__ float feat[108];
    __shared__ float hidm[108];
    __shared__ float st[9];
    int b = blockIdx.x, tid = threadIdx.x;
    int w = tid >> 6, lane = tid & 63;
    int len = lengths[b];
    if (tid < 9) st[tid] = statics[b * 9 + tid];
    for (int idx = tid; idx < 288; idx += 256) ((float*)ps2)[idx] = 0.f;
    __syncthreads();
#pragma unroll
    for (int c0 = 0; c0 < 128; c0 += 64) {
        int col = c0 + lane;
        if (col < 72) {
            float s = 0.f;
            for (int t = w; t < len; t += 4) s += h[((size_t)t * BB + b) * 72 + col];
            ps2[w][col] = s;
        }
    }
    __syncthreads();
    if (tid < 72)
        feat[tid] = (ps2[0][tid] + ps2[1][tid] + ps2[2][tid] + ps2[3][tid]) / ((float)len + 1.0f);
    if (tid >= 128 && tid < 164) {
        int o = tid - 128;
        float a = b_emb[o];
#pragma unroll
        for (int i = 0; i < 9; ++i) a = fmaf(st[i], W_emb[o * 9 + i], a);
        feat[72 + o] = a;
    }
    __syncthreads();
    if (tid < 108) {
        float a = bb1[tid];
        for (int i = 0; i < 108; ++i) a = fmaf(feat[i], w1[tid * 108 + i], a);
        hidm[tid] = fmaxf(a, 0.f);
    }
    __syncthreads();
    if (tid < 2) {
        float a = bb2[tid];
        for (int i = 0; i < 108; ++i) a = fmaf(hidm[i], w2[tid * 108 + i], a);
        out[b * 2 + tid] = a;
    }
}

// ---------------------------------------------------------------- final distance reduce
__global__ void k_dist(const float* __restrict__ rowsum, float* __restrict__ out) {
    __shared__ float red[256];
    int tid = threadIdx.x;
    red[tid] = rowsum[tid];
    __syncthreads();
    for (int s = 128; s > 0; s >>= 1) { if (tid < s) red[tid] += red[tid + s]; __syncthreads(); }
    if (tid == 0) out[2 * BB] = red[0] / 65536.0f;
}

extern "C" void kernel_launch(void* const* d_in, const int* in_sizes, int n_in,
                              void* d_out, int out_size, void* d_ws, size_t ws_size,
                              hipStream_t stream) {
    const float* src     = (const float*)d_in[0];
    const float* statics = (const float*)d_in[1];
    const float* times   = (const float*)d_in[2];
    const int*   lengths = (const int*)d_in[3];
    const float* W_enc = (const float*)d_in[4];  const float* b_enc = (const float*)d_in[5];
    const float* W_emb = (const float*)d_in[6];  const float* b_emb = (const float*)d_in[7];
    const float* Wq = (const float*)d_in[8];     const float* bq = (const float*)d_in[9];
    const float* Wk = (const float*)d_in[10];    const float* bk = (const float*)d_in[11];
    const float* Wv = (const float*)d_in[12];    const float* bv = (const float*)d_in[13];
    const float* Wskip = (const float*)d_in[14]; const float* bskip = (const float*)d_in[15];
    const float* enc_in_w = (const float*)d_in[16];  const float* enc_in_b = (const float*)d_in[17];
    const float* enc_out_w = (const float*)d_in[18]; const float* enc_out_b = (const float*)d_in[19];
    const float* ff1_w = (const float*)d_in[20]; const float* ff1_b = (const float*)d_in[21];
    const float* ff2_w = (const float*)d_in[22]; const float* ff2_b = (const float*)d_in[23];
    const float* ln1_g = (const float*)d_in[24]; const float* ln1_b = (const float*)d_in[25];
    const float* ln2_g = (const float*)d_in[26]; const float* ln2_b = (const float*)d_in[27];
    const float* w1 = (const float*)d_in[28];    const float* bb1 = (const float*)d_in[29];
    const float* w2 = (const float*)d_in[30];    const float* bb2 = (const float*)d_in[31];
    float* out = (float*)d_out;

    float* p = (float*)d_ws;
    float* x    = p; p += (size_t)ROWS * 36;
    float* h    = p; p += (size_t)ROWS * 72;
    float* qkv  = p; p += (size_t)ROWS * 216;
    float* ctx  = p; p += (size_t)ROWS * 72;
    float* qg   = p; p += (size_t)36 * BB * 36;
    float* kg   = p; p += (size_t)36 * BB * 36;
    float* vg   = p; p += (size_t)36 * BB * 36;
    float* Abuf = p; p += (size_t)BB * 1296;
    float* sqv  = p; p += BB;
    float* rsum = p; p += BB;
    float* ts   = p; p += 32;
    unsigned short* Whi  = (unsigned short*)p; p += (2 * 216 * 96) / 2;
    unsigned short* Wlo  = (unsigned short*)p; p += (2 * 216 * 96) / 2;
    unsigned short* F1hi = (unsigned short*)p; p += (2 * 128 * 96) / 2;
    unsigned short* F1lo = (unsigned short*)p; p += (2 * 128 * 96) / 2;
    unsigned short* F2hi = (unsigned short*)p; p += (2 * 72 * 128) / 2;
    unsigned short* F2lo = (unsigned short*)p; p += (2 * 72 * 128) / 2;
    unsigned short* Ohi  = (unsigned short*)p; p += (2 * 72 * 96) / 2;
    unsigned short* Olo  = (unsigned short*)p; p += (2 * 72 * 96) / 2;

    k_prep<<<162, 256, 0, stream>>>(enc_in_w, ff1_w, ff2_w, enc_out_w,
                                    Whi, Wlo, F1hi, F1lo, F2hi, F2lo, Ohi, Olo, ts);
    k_enc1<<<dim3(TT, 4), 256, 0, stream>>>(src, W_enc, b_enc, x);
    k_enc2<<<dim3(TT, 4), 256, 0, stream>>>(x, Wskip, bskip, h);
    k_pe<<<(ROWS * 36) / 256, 256, 0, stream>>>(times, ts, h);
    k_graph_qkv<<<dim3(36, 12), 256, 0, stream>>>(x, Wq, bq, Wk, bk, Wv, bv, qg, kg, vg);
    k_graph_attn<<<BB, 128, 0, stream>>>(qg, kg, vg, h, Abuf, sqv);
    k_gram<<<BB, 256, 0, stream>>>(Abuf, sqv, rsum);
    for (int l = 0; l < 2; ++l) {
        k_qkv<<<ROWS / 64, 256, 0, stream>>>(h, Whi + (size_t)l * 216 * 96,
                                             Wlo + (size_t)l * 216 * 96,
                                             enc_in_b + l * 216, qkv);
        k_attn<<<BB * 4, 256, 0, stream>>>(qkv, lengths, ctx);
        k_outln<<<ROWS / 64, 256, 0, stream>>>(ctx, Ohi + (size_t)l * 72 * 96,
                                               Olo + (size_t)l * 72 * 96, enc_out_b + l * 72,
                                               ln1_g + l * 72, ln1_b + l * 72, h);
        k_ffln<<<ROWS / 64, 256, 0, stream>>>(F1hi + (size_t)l * 128 * 96,
                                              F1lo + (size_t)l * 128 * 96, ff1_b + l * 128,
                                              F2hi + (size_t)l * 72 * 128,
                                              F2lo + (size_t)l * 72 * 128, ff2_b + l * 72,
                                              ln2_g + l * 72, ln2_b + l * 72, h);
    }
    k_head<<<BB, 256, 0, stream>>>(h, lengths, statics, W_emb, b_emb, w1, bb1, w2, bb2, out);
    k_dist<<<1, 256, 0, stream>>>(rsum, out);
}

// Round 16
// 473.958 us; speedup vs baseline: 1.2835x; 1.0556x over previous
//
#include <hip/hip_runtime.h>

#define TT 215
#define BB 256
#define ROWS (TT * BB)  // 55040 = 860 * 64

typedef __attribute__((ext_vector_type(8))) short short8;   // 8 bf16 = 4 VGPRs
typedef __attribute__((ext_vector_type(4))) float f32x4;    // MFMA acc

__device__ __forceinline__ unsigned short f2bf_rn(float x) {
    unsigned int u = __float_as_uint(x);
    u = u + 0x7FFFu + ((u >> 16) & 1u);   // round-to-nearest-even bf16
    return (unsigned short)(u >> 16);
}
__device__ __forceinline__ float bf2f(unsigned short b) {
    return __uint_as_float(((unsigned int)b) << 16);
}

// ---------------------------------------------------------------- one-shot prep: timescales + split-bf16 weights
// enc_in [2][216][96], ff1 [2][128][96], ff2 [2][72][128], Wout [2][72][96]
__global__ void k_prep(const float* __restrict__ enc_in_w, const float* __restrict__ ff1_w,
                       const float* __restrict__ ff2_w, const float* __restrict__ enc_out_w,
                       unsigned short* __restrict__ Whi, unsigned short* __restrict__ Wlo,
                       unsigned short* __restrict__ F1hi, unsigned short* __restrict__ F1lo,
                       unsigned short* __restrict__ F2hi, unsigned short* __restrict__ F2lo,
                       unsigned short* __restrict__ Ohi, unsigned short* __restrict__ Olo,
                       float* __restrict__ ts) {
    int g = blockIdx.x * 256 + threadIdx.x;
    if (g < 18) ts[g] = (float)pow(215.0, (double)g / 17.0);  // matches np float64 215**linspace
    if (g < 2 * 216 * 96) {
        int l = g / (216 * 96), rem = g % (216 * 96);
        int o = rem / 96, k = rem % 96;
        float v = (k < 72) ? enc_in_w[((size_t)l * 216 + o) * 72 + k] : 0.f;
        unsigned short hi = f2bf_rn(v);
        Whi[g] = hi; Wlo[g] = f2bf_rn(v - bf2f(hi));
    }
    if (g < 2 * 128 * 96) {
        int l = g / (128 * 96), rem = g % (128 * 96);
        int j = rem / 96, k = rem % 96;
        float v = (k < 72) ? ff1_w[((size_t)l * 128 + j) * 72 + k] : 0.f;
        unsigned short hi = f2bf_rn(v);
        F1hi[g] = hi; F1lo[g] = f2bf_rn(v - bf2f(hi));
    }
    if (g < 2 * 72 * 128) {  // ff2 already [o][j] = B[n][k], K=128
        float v = ff2_w[g];
        unsigned short hi = f2bf_rn(v);
        F2hi[g] = hi; F2lo[g] = f2bf_rn(v - bf2f(hi));
    }
    if (g < 2 * 72 * 96) {
        int l = g / (72 * 96), rem = g % (72 * 96);
        int o = rem / 96, k = rem % 96;
        float v = (k < 72) ? enc_out_w[((size_t)l * 72 + o) * 72 + k] : 0.f;
        unsigned short hi = f2bf_rn(v);
        Ohi[g] = hi; Olo[g] = f2bf_rn(v - bf2f(hi));
    }
}

// ---------------------------------------------------------------- x = (src[:,:,:36] @ W_enc.T + b)*6 ; grid (215,4)
__global__ __launch_bounds__(256, 1) void k_enc1(const float* __restrict__ src,
                                                 const float* __restrict__ W,
                                                 const float* __restrict__ bias,
                                                 float* __restrict__ x) {
    int row = blockIdx.x * 256 + threadIdx.x;
    int o0 = blockIdx.y * 9;
    float s[36];
    const float4* sv = (const float4*)(src + (size_t)row * 72);
#pragma unroll
    for (int k = 0; k < 9; ++k) {
        float4 v = sv[k];
        s[4 * k] = v.x; s[4 * k + 1] = v.y; s[4 * k + 2] = v.z; s[4 * k + 3] = v.w;
    }
    float* xp = x + (size_t)row * 36 + o0;
#pragma unroll
    for (int o = 0; o < 9; ++o) {
        float a = bias[o0 + o];
        const float* w = W + (size_t)(o0 + o) * 36;
#pragma unroll
        for (int i = 0; i < 36; ++i) a = fmaf(s[i], w[i], a);
        xp[o] = a * 6.0f;
    }
}

// ---------------------------------------------------------------- h[:,:, :36] = x @ Wskip.T + b ; grid (215,4)
__global__ __launch_bounds__(256, 1) void k_enc2(const float* __restrict__ x,
                                                 const float* __restrict__ W,
                                                 const float* __restrict__ bias,
                                                 float* __restrict__ h) {
    int row = blockIdx.x * 256 + threadIdx.x;
    int o0 = blockIdx.y * 9;
    float xr[36];
    const float4* xv = (const float4*)(x + (size_t)row * 36);
#pragma unroll
    for (int k = 0; k < 9; ++k) {
        float4 v = xv[k];
        xr[4 * k] = v.x; xr[4 * k + 1] = v.y; xr[4 * k + 2] = v.z; xr[4 * k + 3] = v.w;
    }
    float* hp = h + (size_t)row * 72 + o0;
#pragma unroll
    for (int o = 0; o < 9; ++o) {
        float a = bias[o0 + o];
        const float* w = W + (size_t)(o0 + o) * 36;
#pragma unroll
        for (int i = 0; i < 36; ++i) a = fmaf(xr[i], w[i], a);
        hp[o] = a;
    }
}

// ---------------------------------------------------------------- h[:,:,36:] = pe ; elementwise
__global__ __launch_bounds__(256) void k_pe(const float* __restrict__ times,
                                            const float* __restrict__ ts,
                                            float* __restrict__ h) {
    int idx = blockIdx.x * 256 + threadIdx.x;  // < ROWS*36
    int d = idx % 36, row = idx / 36;
    float t = times[row];
    float val;
    if (d < 18) val = sinf(t / ts[d]);
    else        val = cosf(t / ts[d - 18]);
    h[(size_t)row * 72 + 36 + d] = val;
}

// ---------------------------------------------------------------- graph q|k|v ; grid (36, 12): mat = y>>2, o0 = (y&3)*9
__global__ __launch_bounds__(256, 1) void k_graph_qkv(const float* __restrict__ x,
                                                      const float* __restrict__ Wq, const float* __restrict__ bq,
                                                      const float* __restrict__ Wk, const float* __restrict__ bk,
                                                      const float* __restrict__ Wv, const float* __restrict__ bv,
                                                      float* __restrict__ qg, float* __restrict__ kg,
                                                      float* __restrict__ vg) {
    int row = blockIdx.x * 256 + threadIdx.x;  // < 9216
    int mat = blockIdx.y >> 2;
    int o0 = (blockIdx.y & 3) * 9;
    const float* W; const float* bias; float* out;
    if (mat == 0)      { W = Wq; bias = bq; out = qg; }
    else if (mat == 1) { W = Wk; bias = bk; out = kg; }
    else               { W = Wv; bias = bv; out = vg; }
    float xr[36];
    const float4* xv = (const float4*)(x + (size_t)row * 36);
#pragma unroll
    for (int k = 0; k < 9; ++k) {
        float4 v = xv[k];
        xr[4 * k] = v.x; xr[4 * k + 1] = v.y; xr[4 * k + 2] = v.z; xr[4 * k + 3] = v.w;
    }
    float* op = out + (size_t)row * 36 + o0;
#pragma unroll
    for (int o = 0; o < 9; ++o) {
        float a = bias[o0 + o];
        const float* w = W + (size_t)(o0 + o) * 36;
#pragma unroll
        for (int i = 0; i < 36; ++i) a = fmaf(xr[i], w[i], a);
        op[o] = a;
    }
}

// ---------------------------------------------------------------- graph attention per batch; h[:36,:,:36] += msg
// Also emits A as split-bf16 [256][1312] (K zero-padded) for the MFMA Gram.
__global__ void k_graph_attn(const float* __restrict__ qg, const float* __restrict__ kg,
                             const float* __restrict__ vg, float* __restrict__ h,
                             unsigned short* __restrict__ Ahi, unsigned short* __restrict__ Alo,
                             float* __restrict__ sqv) {
    __shared__ float q[1296], k[1296], v[1296], A[1296];
    __shared__ float red[128];
    int b = blockIdx.x, tid = threadIdx.x;
    for (int i = tid; i < 1296; i += 128) {
        int t = i / 36, e = i % 36;
        int g = (t * BB + b) * 36 + e;
        q[i] = qg[g]; k[i] = kg[g]; v[i] = vg[g];
    }
    __syncthreads();
    for (int i = tid; i < 1296; i += 128) {
        int r = i / 36, c = i % 36;
        float a = 0.f;
#pragma unroll
        for (int e = 0; e < 36; ++e) a = fmaf(q[r * 36 + e], k[c * 36 + e], a);
        A[i] = a * (1.0f / 6.0f);
    }
    __syncthreads();
    if (tid < 36) {
        float m = -1e30f;
        for (int j = 0; j < 36; ++j) m = fmaxf(m, A[tid * 36 + j]);
        float s = 0.f;
        for (int j = 0; j < 36; ++j) { float e = expf(A[tid * 36 + j] - m); A[tid * 36 + j] = e; s += e; }
        float inv = 1.0f / s;
        for (int j = 0; j < 36; ++j) A[tid * 36 + j] *= inv;
    }
    __syncthreads();
    float lsq = 0.f;
    for (int i = tid; i < 1296; i += 128) {
        float a = A[i];
        unsigned short hi = f2bf_rn(a);
        Ahi[(size_t)b * 1312 + i] = hi;
        Alo[(size_t)b * 1312 + i] = f2bf_rn(a - bf2f(hi));
        lsq = fmaf(a, a, lsq);
        int r = i / 36, e = i % 36;
        float m = 0.f;
#pragma unroll
        for (int j = 0; j < 36; ++j) m = fmaf(A[r * 36 + j], v[j * 36 + e], m);
        h[((size_t)r * BB + b) * 72 + e] += m;
    }
    if (tid < 16) {  // zero K-pad 1296..1311
        Ahi[(size_t)b * 1312 + 1296 + tid] = 0;
        Alo[(size_t)b * 1312 + 1296 + tid] = 0;
    }
    red[tid] = lsq;
    __syncthreads();
    for (int s = 64; s > 0; s >>= 1) { if (tid < s) red[tid] += red[tid + s]; __syncthreads(); }
    if (tid == 0) sqv[b] = red[0];
}

// ---------------------------------------------------------------- Gram via MFMA: G = A.A^T ; 32x32 tile per block,
// 4 waves x one 16x16 tile; epilogue d2 -> sqrt -> block partial sum.
__global__ __launch_bounds__(256, 1) void k_gram(const unsigned short* __restrict__ Ahi,
                                                 const unsigned short* __restrict__ Alo,
                                                 const float* __restrict__ sqv,
                                                 float* __restrict__ bpart) {
    __shared__ float red[4];
    int tid = threadIdx.x;
    int w = tid >> 6;
    int lane = tid & 63;
    int n16 = lane & 15;
    int quad = lane >> 4;
    int i0 = (blockIdx.x >> 3) * 32 + (w >> 1) * 16;
    int j0 = (blockIdx.x & 7) * 32 + (w & 1) * 16;
    const short8* Ari = (const short8*)(Ahi + (size_t)(i0 + n16) * 1312);
    const short8* Arl = (const short8*)(Alo + (size_t)(i0 + n16) * 1312);
    const short8* Bri = (const short8*)(Ahi + (size_t)(j0 + n16) * 1312);
    const short8* Brl = (const short8*)(Alo + (size_t)(j0 + n16) * 1312);
    f32x4 acc = (f32x4){0.f, 0.f, 0.f, 0.f};
    for (int k2 = 0; k2 < 41; ++k2) {
        int ko = k2 * 4 + quad;
        short8 ah = Ari[ko], al = Arl[ko];
        short8 bh = Bri[ko], bl = Brl[ko];
        acc = __builtin_amdgcn_mfma_f32_16x16x32_bf16(ah, bh, acc, 0, 0, 0);
        acc = __builtin_amdgcn_mfma_f32_16x16x32_bf16(ah, bl, acc, 0, 0, 0);
        acc = __builtin_amdgcn_mfma_f32_16x16x32_bf16(al, bh, acc, 0, 0, 0);
    }
    // C-layout: col=n16 -> j, row=quad*4+reg -> i
    float part = 0.f;
#pragma unroll
    for (int reg = 0; reg < 4; ++reg) {
        int i = i0 + quad * 4 + reg;
        int j = j0 + n16;
        float d2 = fmaxf(sqv[i] + sqv[j] - 2.0f * acc[reg], 0.0f);
        part += (d2 > 0.0f) ? sqrtf(d2) : 0.0f;
    }
#pragma unroll
    for (int m = 1; m < 64; m <<= 1) part += __shfl_xor(part, m);
    if (lane == 0) red[w] = part;
    __syncthreads();
    if (tid == 0) bpart[blockIdx.x] = red[0] + red[1] + red[2] + red[3];
}

// ---------------------------------------------------------------- qkv = h @ W_in.T + b ; MFMA split-bf16
__global__ __launch_bounds__(256, 1) void k_qkv(const float* __restrict__ h,
                                                const unsigned short* __restrict__ Whi,
                                                const unsigned short* __restrict__ Wlo,
                                                const float* __restrict__ bias,
                                                float* __restrict__ qkv) {
    int tid = threadIdx.x;
    int w = tid >> 6;
    int lane = tid & 63;
    int n16 = lane & 15;
    int quad = lane >> 4;
    int m0 = blockIdx.x * 64 + w * 16;
    int r = m0 + n16;
    short8 Ahi[3], Alo[3];
#pragma unroll
    for (int s = 0; s < 3; ++s) {
        int k0 = s * 32 + quad * 8;
        float v[8];
        if (k0 < 72) {
            const float4* ap = (const float4*)(h + (size_t)r * 72 + k0);
            float4 v0 = ap[0], v1 = ap[1];
            v[0] = v0.x; v[1] = v0.y; v[2] = v0.z; v[3] = v0.w;
            v[4] = v1.x; v[5] = v1.y; v[6] = v1.z; v[7] = v1.w;
        } else {
#pragma unroll
            for (int j = 0; j < 8; ++j) v[j] = 0.f;
        }
        short8 ph, pl;
#pragma unroll
        for (int j = 0; j < 8; ++j) {
            unsigned short hi = f2bf_rn(v[j]);
            ph[j] = (short)hi;
            pl[j] = (short)f2bf_rn(v[j] - bf2f(hi));
        }
        Ahi[s] = ph; Alo[s] = pl;
    }
    f32x4 acc[14];
#pragma unroll
    for (int t = 0; t < 14; ++t) acc[t] = (f32x4){0.f, 0.f, 0.f, 0.f};
#pragma unroll
    for (int t = 0; t < 14; ++t) {
        int o = t * 16 + n16;
        int oc = (o > 215) ? 215 : o;
        const short8* bh = (const short8*)(Whi + (size_t)oc * 96);
        const short8* bl = (const short8*)(Wlo + (size_t)oc * 96);
        f32x4 a = acc[t];
#pragma unroll
        for (int s = 0; s < 3; ++s) {
            short8 Bh = bh[s * 4 + quad];
            short8 Bl = bl[s * 4 + quad];
            a = __builtin_amdgcn_mfma_f32_16x16x32_bf16(Ahi[s], Bh, a, 0, 0, 0);
            a = __builtin_amdgcn_mfma_f32_16x16x32_bf16(Ahi[s], Bl, a, 0, 0, 0);
            a = __builtin_amdgcn_mfma_f32_16x16x32_bf16(Alo[s], Bh, a, 0, 0, 0);
        }
        acc[t] = a;
    }
#pragma unroll
    for (int t = 0; t < 14; ++t) {
        int col = t * 16 + n16;
        if (col < 216) {
            float b = bias[col];
#pragma unroll
            for (int reg = 0; reg < 4; ++reg) {
                int row = m0 + quad * 4 + reg;
                qkv[(size_t)row * 216 + col] = acc[t][reg] + b;
            }
        }
    }
}

// ---------------------------------------------------------------- masked MHA v6: MFMA flash per (b,head)
__global__ __launch_bounds__(256, 1) void k_attn(const float* __restrict__ qkv,
                                                 const int* __restrict__ lengths,
                                                 float* __restrict__ ctx) {
    __shared__ __attribute__((aligned(16))) unsigned short Kb[215 * 40];   // [key][40], cols 18..39 zero
    __shared__ __attribute__((aligned(16))) unsigned short Vt[32 * 232];   // [d][232], rows 18..31 zero
    __shared__ __attribute__((aligned(16))) unsigned short Pw[4][16 * 232];// per-wave P strip
    int b = blockIdx.x & (BB - 1);
    int hh = blockIdx.x >> 8;
    int tid = threadIdx.x;
    int len = lengths[b];
    for (int i = tid; i < (215 * 40) / 2; i += 256) ((unsigned int*)Kb)[i] = 0u;
    for (int i = tid; i < (32 * 232) / 2; i += 256) ((unsigned int*)Vt)[i] = 0u;
    __syncthreads();
    for (int i = tid; i < len * 18; i += 256) {
        int s = i / 18, d = i % 18;
        size_t base2 = ((size_t)s * BB + b) * 216 + hh * 18 + d;
        Kb[s * 40 + d] = f2bf_rn(qkv[base2 + 72]);
        Vt[d * 232 + s] = f2bf_rn(qkv[base2 + 144]);
    }
    __syncthreads();
    int w = tid >> 6;
    int lane = tid & 63;
    int n16 = lane & 15;
    int quad = lane >> 4;
    const float scale = 0.23570226039551587f;  // 1/sqrt(18); folded into Q
    int nk2 = (len + 31) >> 5;
    int nkt = nk2 * 2;
    int nstrips = (len + 15) >> 4;
    unsigned short* P = &Pw[w][0];
    for (int strip = w; strip < nstrips; strip += 4) {
        int q0 = strip * 16;
        int qr = q0 + n16; if (qr > 214) qr = 214;
        float qv[8];
#pragma unroll
        for (int j = 0; j < 8; ++j) qv[j] = 0.f;
        {
            const float* qp = qkv + ((size_t)qr * BB + b) * 216 + hh * 18;
            int d0 = quad * 8;
            if (d0 < 16) {
                const float2* q2 = (const float2*)(qp + d0);
                float2 a0 = q2[0], a1 = q2[1], a2 = q2[2], a3 = q2[3];
                qv[0] = a0.x; qv[1] = a0.y; qv[2] = a1.x; qv[3] = a1.y;
                qv[4] = a2.x; qv[5] = a2.y; qv[6] = a3.x; qv[7] = a3.y;
            } else if (d0 == 16) {
                qv[0] = qp[16]; qv[1] = qp[17];
            }
        }
        short8 Qhi, Qlo;
#pragma unroll
        for (int j = 0; j < 8; ++j) {
            float v = qv[j] * scale;
            unsigned short hi = f2bf_rn(v);
            Qhi[j] = (short)hi;
            Qlo[j] = (short)f2bf_rn(v - bf2f(hi));
        }
        float lsum[4] = {0.f, 0.f, 0.f, 0.f};
        for (int kt = 0; kt < nkt; ++kt) {
            int key = kt * 16 + n16;
            int kr = (key > 214) ? 214 : key;
            short8 Bk = *(const short8*)(Kb + kr * 40 + quad * 8);
            f32x4 S = (f32x4){0.f, 0.f, 0.f, 0.f};
            S = __builtin_amdgcn_mfma_f32_16x16x32_bf16(Qlo, Bk, S, 0, 0, 0);
            S = __builtin_amdgcn_mfma_f32_16x16x32_bf16(Qhi, Bk, S, 0, 0, 0);
#pragma unroll
            for (int reg = 0; reg < 4; ++reg) {
                float p = (key < len) ? __expf(S[reg]) : 0.f;
                lsum[reg] += p;
                P[(quad * 4 + reg) * 232 + kt * 16 + n16] = f2bf_rn(p);
            }
        }
#pragma unroll
        for (int m = 1; m < 16; m <<= 1) {
#pragma unroll
            for (int reg = 0; reg < 4; ++reg) lsum[reg] += __shfl_xor(lsum[reg], m);
        }
        f32x4 o0 = (f32x4){0.f, 0.f, 0.f, 0.f};
        f32x4 o1 = (f32x4){0.f, 0.f, 0.f, 0.f};
        for (int k2 = 0; k2 < nk2; ++k2) {
            short8 Af = *(const short8*)(P + n16 * 232 + k2 * 32 + quad * 8);
            short8 Bv0 = *(const short8*)(Vt + n16 * 232 + k2 * 32 + quad * 8);
            short8 Bv1 = *(const short8*)(Vt + (16 + n16) * 232 + k2 * 32 + quad * 8);
            o0 = __builtin_amdgcn_mfma_f32_16x16x32_bf16(Af, Bv0, o0, 0, 0, 0);
            o1 = __builtin_amdgcn_mfma_f32_16x16x32_bf16(Af, Bv1, o1, 0, 0, 0);
        }
#pragma unroll
        for (int reg = 0; reg < 4; ++reg) {
            int t = q0 + quad * 4 + reg;
            if (t < len) {
                float inv = 1.0f / lsum[reg];
                float* cb = ctx + ((size_t)t * BB + b) * 72 + hh * 18;
                cb[n16] = o0[reg] * inv;
                if (n16 < 2) cb[16 + n16] = o1[reg] * inv;
            }
        }
    }
}

// ---------------------------------------------------------------- h = LN(h + ctx@Wout.T+b) ; MFMA split-bf16
__global__ __launch_bounds__(256, 1) void k_outln(const float* __restrict__ ctx,
                                                  const unsigned short* __restrict__ Ohi,
                                                  const unsigned short* __restrict__ Olo,
                                                  const float* __restrict__ bias,
                                                  const float* __restrict__ g,
                                                  const float* __restrict__ beta,
                                                  float* __restrict__ h) {
    int tid = threadIdx.x;
    int w = tid >> 6;
    int lane = tid & 63;
    int n16 = lane & 15;
    int quad = lane >> 4;
    int m0 = blockIdx.x * 64 + w * 16;
    int r = m0 + n16;
    short8 Ahi[3], Alo[3];
#pragma unroll
    for (int s = 0; s < 3; ++s) {
        int k0 = s * 32 + quad * 8;
        float v[8];
        if (k0 < 72) {
            const float4* ap = (const float4*)(ctx + (size_t)r * 72 + k0);
            float4 v0 = ap[0], v1 = ap[1];
            v[0] = v0.x; v[1] = v0.y; v[2] = v0.z; v[3] = v0.w;
            v[4] = v1.x; v[5] = v1.y; v[6] = v1.z; v[7] = v1.w;
        } else {
#pragma unroll
            for (int j = 0; j < 8; ++j) v[j] = 0.f;
        }
        short8 ph, pl;
#pragma unroll
        for (int j = 0; j < 8; ++j) {
            unsigned short hi = f2bf_rn(v[j]);
            ph[j] = (short)hi;
            pl[j] = (short)f2bf_rn(v[j] - bf2f(hi));
        }
        Ahi[s] = ph; Alo[s] = pl;
    }
    f32x4 acc[5];
#pragma unroll
    for (int t = 0; t < 5; ++t) acc[t] = (f32x4){0.f, 0.f, 0.f, 0.f};
#pragma unroll
    for (int t = 0; t < 5; ++t) {
        int o = t * 16 + n16;
        int oc = (o > 71) ? 71 : o;
        const short8* bh = (const short8*)(Ohi + (size_t)oc * 96);
        const short8* bl = (const short8*)(Olo + (size_t)oc * 96);
        f32x4 a = acc[t];
#pragma unroll
        for (int s = 0; s < 3; ++s) {
            short8 Bh = bh[s * 4 + quad];
            short8 Bl = bl[s * 4 + quad];
            a = __builtin_amdgcn_mfma_f32_16x16x32_bf16(Ahi[s], Bh, a, 0, 0, 0);
            a = __builtin_amdgcn_mfma_f32_16x16x32_bf16(Ahi[s], Bl, a, 0, 0, 0);
            a = __builtin_amdgcn_mfma_f32_16x16x32_bf16(Alo[s], Bh, a, 0, 0, 0);
        }
        acc[t] = a;
    }
    float vals[5][4];
#pragma unroll
    for (int t = 0; t < 5; ++t) {
        int o = t * 16 + n16;
        bool valid = (o < 72);
        float bb = valid ? bias[o] : 0.f;
#pragma unroll
        for (int reg = 0; reg < 4; ++reg) {
            int row = m0 + quad * 4 + reg;
            float hv = valid ? h[(size_t)row * 72 + o] : 0.f;
            vals[t][reg] = acc[t][reg] + bb + hv;
        }
    }
#pragma unroll
    for (int reg = 0; reg < 4; ++reg) {
        float s = 0.f, q = 0.f;
#pragma unroll
        for (int t = 0; t < 5; ++t) {
            int o = t * 16 + n16;
            if (o < 72) { s += vals[t][reg]; q = fmaf(vals[t][reg], vals[t][reg], q); }
        }
#pragma unroll
        for (int m = 1; m < 16; m <<= 1) { s += __shfl_xor(s, m); q += __shfl_xor(q, m); }
        float mu = s / 72.0f;
        float var = fmaxf(q / 72.0f - mu * mu, 0.0f);
        float rstd = 1.0f / sqrtf(var + 1e-5f);
        int row = m0 + quad * 4 + reg;
#pragma unroll
        for (int t = 0; t < 5; ++t) {
            int o = t * 16 + n16;
            if (o < 72)
                h[(size_t)row * 72 + o] = (vals[t][reg] - mu) * rstd * g[o] + beta[o];
        }
    }
}

// ---------------------------------------------------------------- h = LN(h + relu(h@ff1.T)@ff2.T+b) ; MFMA split-bf16
__global__ __launch_bounds__(256, 1) void k_ffln(const unsigned short* __restrict__ F1hi,
                                                 const unsigned short* __restrict__ F1lo,
                                                 const float* __restrict__ b1,
                                                 const unsigned short* __restrict__ F2hi,
                                                 const unsigned short* __restrict__ F2lo,
                                                 const float* __restrict__ b2,
                                                 const float* __restrict__ g,
                                                 const float* __restrict__ beta,
                                                 float* __restrict__ h) {
    __shared__ float hid[64][129];
    int tid = threadIdx.x;
    int w = tid >> 6;
    int lane = tid & 63;
    int n16 = lane & 15;
    int quad = lane >> 4;
    int m0 = blockIdx.x * 64 + w * 16;
    int r = m0 + n16;
    short8 Ahi[3], Alo[3];
#pragma unroll
    for (int s = 0; s < 3; ++s) {
        int k0 = s * 32 + quad * 8;
        float v[8];
        if (k0 < 72) {
            const float4* ap = (const float4*)(h + (size_t)r * 72 + k0);
            float4 v0 = ap[0], v1 = ap[1];
            v[0] = v0.x; v[1] = v0.y; v[2] = v0.z; v[3] = v0.w;
            v[4] = v1.x; v[5] = v1.y; v[6] = v1.z; v[7] = v1.w;
        } else {
#pragma unroll
            for (int j = 0; j < 8; ++j) v[j] = 0.f;
        }
        short8 ph, pl;
#pragma unroll
        for (int j = 0; j < 8; ++j) {
            unsigned short hi = f2bf_rn(v[j]);
            ph[j] = (short)hi;
            pl[j] = (short)f2bf_rn(v[j] - bf2f(hi));
        }
        Ahi[s] = ph; Alo[s] = pl;
    }
#pragma unroll
    for (int t = 0; t < 8; ++t) {
        int j = t * 16 + n16;
        const short8* bh = (const short8*)(F1hi + (size_t)j * 96);
        const short8* bl = (const short8*)(F1lo + (size_t)j * 96);
        f32x4 a = (f32x4){0.f, 0.f, 0.f, 0.f};
#pragma unroll
        for (int s = 0; s < 3; ++s) {
            short8 Bh = bh[s * 4 + quad];
            short8 Bl = bl[s * 4 + quad];
            a = __builtin_amdgcn_mfma_f32_16x16x32_bf16(Ahi[s], Bh, a, 0, 0, 0);
            a = __builtin_amdgcn_mfma_f32_16x16x32_bf16(Ahi[s], Bl, a, 0, 0, 0);
            a = __builtin_amdgcn_mfma_f32_16x16x32_bf16(Alo[s], Bh, a, 0, 0, 0);
        }
        float bb = b1[j];
#pragma unroll
        for (int reg = 0; reg < 4; ++reg)
            hid[w * 16 + quad * 4 + reg][j] = fmaxf(a[reg] + bb, 0.f);
    }
    // wave-private rows: in-wave lgkmcnt ordering suffices, no barrier
    short8 A2hi[4], A2lo[4];
#pragma unroll
    for (int s = 0; s < 4; ++s) {
        const float* hp = &hid[w * 16 + n16][s * 32 + quad * 8];
        short8 ph, pl;
#pragma unroll
        for (int j = 0; j < 8; ++j) {
            float v = hp[j];
            unsigned short hi = f2bf_rn(v);
            ph[j] = (short)hi;
            pl[j] = (short)f2bf_rn(v - bf2f(hi));
        }
        A2hi[s] = ph; A2lo[s] = pl;
    }
    f32x4 acc[5];
#pragma unroll
    for (int t = 0; t < 5; ++t) acc[t] = (f32x4){0.f, 0.f, 0.f, 0.f};
#pragma unroll
    for (int t = 0; t < 5; ++t) {
        int o = t * 16 + n16;
        int oc = (o > 71) ? 71 : o;
        const short8* bh = (const short8*)(F2hi + (size_t)oc * 128);
        const short8* bl = (const short8*)(F2lo + (size_t)oc * 128);
        f32x4 a = acc[t];
#pragma unroll
        for (int s = 0; s < 4; ++s) {
            short8 Bh = bh[s * 4 + quad];
            short8 Bl = bl[s * 4 + quad];
            a = __builtin_amdgcn_mfma_f32_16x16x32_bf16(A2hi[s], Bh, a, 0, 0, 0);
            a = __builtin_amdgcn_mfma_f32_16x16x32_bf16(A2hi[s], Bl, a, 0, 0, 0);
            a = __builtin_amdgcn_mfma_f32_16x16x32_bf16(A2lo[s], Bh, a, 0, 0, 0);
        }
        acc[t] = a;
    }
    float vals[5][4];
#pragma unroll
    for (int t = 0; t < 5; ++t) {
        int o = t * 16 + n16;
        bool valid = (o < 72);
        float bb = valid ? b2[o] : 0.f;
#pragma unroll
        for (int reg = 0; reg < 4; ++reg) {
            int row = m0 + quad * 4 + reg;
            float hv = valid ? h[(size_t)row * 72 + o] : 0.f;
            vals[t][reg] = acc[t][reg] + bb + hv;
        }
    }
#pragma unroll
    for (int reg = 0; reg < 4; ++reg) {
        float s = 0.f, q = 0.f;
#pragma unroll
        for (int t = 0; t < 5; ++t) {
            int o = t * 16 + n16;
            if (o < 72) { s += vals[t][reg]; q = fmaf(vals[t][reg], vals[t][reg], q); }
        }
#pragma unroll
        for (int m = 1; m < 16; m <<= 1) { s += __shfl_xor(s, m); q += __shfl_xor(q, m); }
        float mu = s / 72.0f;
        float var = fmaxf(q / 72.0f - mu * mu, 0.0f);
        float rstd = 1.0f / sqrtf(var + 1e-5f);
        int row = m0 + quad * 4 + reg;
#pragma unroll
        for (int t = 0; t < 5; ++t) {
            int o = t * 16 + n16;
            if (o < 72)
                h[(size_t)row * 72 + o] = (vals[t][reg] - mu) * rstd * g[o] + beta[o];
        }
    }
}

// ---------------------------------------------------------------- masked mean-pool + static emb + 2-layer MLP
__global__ void k_head(const float* __restrict__ h, const int* __restrict__ lengths,
                       const float* __restrict__ statics, const float* __restrict__ W_emb,
                       const float* __restrict__ b_emb, const float* __restrict__ w1,
                       const float* __restrict__ bb1, const float* __restrict__ w2,
                       const float* __restrict__ bb2, float* __restrict__ out) {
    __shared__ float ps2[4][72];
    __shared__ float feat[108];
    __shared__ float hidm[108];
    __shared__ float st[9];
    int b = blockIdx.x, tid = threadIdx.x;
    int w = tid >> 6, lane = tid & 63;
    int len = lengths[b];
    if (tid < 9) st[tid] = statics[b * 9 + tid];
    for (int idx = tid; idx < 288; idx += 256) ((float*)ps2)[idx] = 0.f;
    __syncthreads();
#pragma unroll
    for (int c0 = 0; c0 < 128; c0 += 64) {
        int col = c0 + lane;
        if (col < 72) {
            float s = 0.f;
            for (int t = w; t < len; t += 4) s += h[((size_t)t * BB + b) * 72 + col];
            ps2[w][col] = s;
        }
    }
    __syncthreads();
    if (tid < 72)
        feat[tid] = (ps2[0][tid] + ps2[1][tid] + ps2[2][tid] + ps2[3][tid]) / ((float)len + 1.0f);
    if (tid >= 128 && tid < 164) {
        int o = tid - 128;
        float a = b_emb[o];
#pragma unroll
        for (int i = 0; i < 9; ++i) a = fmaf(st[i], W_emb[o * 9 + i], a);
        feat[72 + o] = a;
    }
    __syncthreads();
    if (tid < 108) {
        float a = bb1[tid];
        for (int i = 0; i < 108; ++i) a = fmaf(feat[i], w1[tid * 108 + i], a);
        hidm[tid] = fmaxf(a, 0.f);
    }
    __syncthreads();
    if (tid < 2) {
        float a = bb2[tid];
        for (int i = 0; i < 108; ++i) a = fmaf(hidm[i], w2[tid * 108 + i], a);
        out[b * 2 + tid] = a;
    }
}

// ---------------------------------------------------------------- final distance reduce (64 block partials)
__global__ void k_dist(const float* __restrict__ bpart, float* __restrict__ out) {
    __shared__ float red[64];
    int tid = threadIdx.x;
    red[tid] = bpart[tid];
    __syncthreads();
    for (int s = 32; s > 0; s >>= 1) { if (tid < s) red[tid] += red[tid + s]; __syncthreads(); }
    if (tid == 0) out[2 * BB] = red[0] / 65536.0f;
}

extern "C" void kernel_launch(void* const* d_in, const int* in_sizes, int n_in,
                              void* d_out, int out_size, void* d_ws, size_t ws_size,
                              hipStream_t stream) {
    const float* src     = (const float*)d_in[0];
    const float* statics = (const float*)d_in[1];
    const float* times   = (const float*)d_in[2];
    const int*   lengths = (const int*)d_in[3];
    const float* W_enc = (const float*)d_in[4];  const float* b_enc = (const float*)d_in[5];
    const float* W_emb = (const float*)d_in[6];  const float* b_emb = (const float*)d_in[7];
    const float* Wq = (const float*)d_in[8];     const float* bq = (const float*)d_in[9];
    const float* Wk = (const float*)d_in[10];    const float* bk = (const float*)d_in[11];
    const float* Wv = (const float*)d_in[12];    const float* bv = (const float*)d_in[13];
    const float* Wskip = (const float*)d_in[14]; const float* bskip = (const float*)d_in[15];
    const float* enc_in_w = (const float*)d_in[16];  const float* enc_in_b = (const float*)d_in[17];
    const float* enc_out_w = (const float*)d_in[18]; const float* enc_out_b = (const float*)d_in[19];
    const float* ff1_w = (const float*)d_in[20]; const float* ff1_b = (const float*)d_in[21];
    const float* ff2_w = (const float*)d_in[22]; const float* ff2_b = (const float*)d_in[23];
    const float* ln1_g = (const float*)d_in[24]; const float* ln1_b = (const float*)d_in[25];
    const float* ln2_g = (const float*)d_in[26]; const float* ln2_b = (const float*)d_in[27];
    const float* w1 = (const float*)d_in[28];    const float* bb1 = (const float*)d_in[29];
    const float* w2 = (const float*)d_in[30];    const float* bb2 = (const float*)d_in[31];
    float* out = (float*)d_out;

    float* p = (float*)d_ws;
    float* x    = p; p += (size_t)ROWS * 36;
    float* h    = p; p += (size_t)ROWS * 72;
    float* qkv  = p; p += (size_t)ROWS * 216;
    float* ctx  = p; p += (size_t)ROWS * 72;
    float* qg   = p; p += (size_t)36 * BB * 36;
    float* kg   = p; p += (size_t)36 * BB * 36;
    float* vg   = p; p += (size_t)36 * BB * 36;
    float* sqv  = p; p += BB;
    float* bpart = p; p += 64;
    float* ts   = p; p += 32;
    unsigned short* GAhi = (unsigned short*)p; p += (BB * 1312) / 2;   // Gram A bf16 hi [256][1312]
    unsigned short* GAlo = (unsigned short*)p; p += (BB * 1312) / 2;
    unsigned short* Whi  = (unsigned short*)p; p += (2 * 216 * 96) / 2;
    unsigned short* Wlo  = (unsigned short*)p; p += (2 * 216 * 96) / 2;
    unsigned short* F1hi = (unsigned short*)p; p += (2 * 128 * 96) / 2;
    unsigned short* F1lo = (unsigned short*)p; p += (2 * 128 * 96) / 2;
    unsigned short* F2hi = (unsigned short*)p; p += (2 * 72 * 128) / 2;
    unsigned short* F2lo = (unsigned short*)p; p += (2 * 72 * 128) / 2;
    unsigned short* Ohi  = (unsigned short*)p; p += (2 * 72 * 96) / 2;
    unsigned short* Olo  = (unsigned short*)p; p += (2 * 72 * 96) / 2;

    k_prep<<<162, 256, 0, stream>>>(enc_in_w, ff1_w, ff2_w, enc_out_w,
                                    Whi, Wlo, F1hi, F1lo, F2hi, F2lo, Ohi, Olo, ts);
    k_enc1<<<dim3(TT, 4), 256, 0, stream>>>(src, W_enc, b_enc, x);
    k_enc2<<<dim3(TT, 4), 256, 0, stream>>>(x, Wskip, bskip, h);
    k_pe<<<(ROWS * 36) / 256, 256, 0, stream>>>(times, ts, h);
    k_graph_qkv<<<dim3(36, 12), 256, 0, stream>>>(x, Wq, bq, Wk, bk, Wv, bv, qg, kg, vg);
    k_graph_attn<<<BB, 128, 0, stream>>>(qg, kg, vg, h, GAhi, GAlo, sqv);
    k_gram<<<64, 256, 0, stream>>>(GAhi, GAlo, sqv, bpart);
    for (int l = 0; l < 2; ++l) {
        k_qkv<<<ROWS / 64, 256, 0, stream>>>(h, Whi + (size_t)l * 216 * 96,
                                             Wlo + (size_t)l * 216 * 96,
                                             enc_in_b + l * 216, qkv);
        k_attn<<<BB * 4, 256, 0, stream>>>(qkv, lengths, ctx);
        k_outln<<<ROWS / 64, 256, 0, stream>>>(ctx, Ohi + (size_t)l * 72 * 96,
                                               Olo + (size_t)l * 72 * 96, enc_out_b + l * 72,
                                               ln1_g + l * 72, ln1_b + l * 72, h);
        k_ffln<<<ROWS / 64, 256, 0, stream>>>(F1hi + (size_t)l * 128 * 96,
                                              F1lo + (size_t)l * 128 * 96, ff1_b + l * 128,
                                              F2hi + (size_t)l * 72 * 128,
                                              F2lo + (size_t)l * 72 * 128, ff2_b + l * 72,
                                              ln2_g + l * 72, ln2_b + l * 72, h);
    }
    k_head<<<BB, 256, 0, stream>>>(h, lengths, statics, W_emb, b_emb, w1, bb1, w2, bb2, out);
    k_dist<<<1, 64, 0, stream>>>(bpart, out);
}